// Round 12
// baseline (244.373 us; speedup 1.0000x reference)
//
#include <hip/hip_runtime.h>
#include <math.h>

#define FI4(p) (*(const float4*)(p))

typedef _Float16 half8 __attribute__((ext_vector_type(8)));
typedef _Float16 half2v __attribute__((ext_vector_type(2)));
typedef float f32x4 __attribute__((ext_vector_type(4)));

__device__ __forceinline__ float gumbelf(float u) {
    return -__logf(-__logf(u + 1e-9f) + 1e-9f);
}

template<int CTRL>
__device__ __forceinline__ int dppmov(int v) {
    return __builtin_amdgcn_update_dpp(v, v, CTRL, 0xF, 0xF, false);
}
__device__ __forceinline__ float wave_max_bcast(float v) {
    v = fmaxf(v, __int_as_float(dppmov<0xB1>(__float_as_int(v))));
    v = fmaxf(v, __int_as_float(dppmov<0x4E>(__float_as_int(v))));
    v = fmaxf(v, __int_as_float(dppmov<0x141>(__float_as_int(v))));
    v = fmaxf(v, __int_as_float(dppmov<0x140>(__float_as_int(v))));
    v = fmaxf(v, __int_as_float(dppmov<0x142>(__float_as_int(v))));
    v = fmaxf(v, __int_as_float(dppmov<0x143>(__float_as_int(v))));
    return __int_as_float(__builtin_amdgcn_readlane(__float_as_int(v), 63));
}
__device__ __forceinline__ float wave_sum_bcast(float v) {
    v += __int_as_float(dppmov<0xB1>(__float_as_int(v)));
    v += __int_as_float(dppmov<0x4E>(__float_as_int(v)));
    v += __int_as_float(dppmov<0x141>(__float_as_int(v)));
    v += __int_as_float(dppmov<0x140>(__float_as_int(v)));
    v += __int_as_float(dppmov<0x142>(__float_as_int(v)));
    v += __int_as_float(dppmov<0x143>(__float_as_int(v)));
    return __int_as_float(__builtin_amdgcn_readlane(__float_as_int(v), 63));
}

__device__ __forceinline__ unsigned ordkey(float f) {
    unsigned x = __float_as_uint(f);
    return x ^ ((unsigned)((int)x >> 31) | 0x80000000u);
}

__device__ __forceinline__ int mbcnt64(unsigned long long m) {
    return __builtin_amdgcn_mbcnt_hi((unsigned)(m >> 32),
           __builtin_amdgcn_mbcnt_lo((unsigned)m, 0));
}

__device__ __forceinline__ void copy8(unsigned long long* dst, const unsigned long long* src) {
    #pragma unroll
    for (int j = 0; j < 8; ++j) dst[j] = src[j];
}

// ties at key == hi filled by smallest n; n = (j>>2)*256 + lane*4 + (j&3)
__device__ __forceinline__ void tie_fill(const unsigned* u, unsigned long long* sel, unsigned hi)
{
    unsigned long long eq[8];
    int mcnt = 0;
    #pragma unroll
    for (int j = 0; j < 8; ++j) {
        sel[j] = __ballot(u[j] > hi);
        eq[j]  = __ballot(u[j] == hi);
        mcnt += __popcll(sel[j]);
    }
    int r = 16 - mcnt;
    #pragma unroll
    for (int jhi = 0; jhi < 2; ++jhi) {
        if (r > 0) {
            unsigned long long any = eq[jhi*4] | eq[jhi*4+1] | eq[jhi*4+2] | eq[jhi*4+3];
            while (any && r > 0) {
                int lane = (int)__builtin_ctzll(any); any &= any - 1;
                #pragma unroll
                for (int jlo = 0; jlo < 4; ++jlo) {
                    int j2 = jhi * 4 + jlo;
                    if (r > 0 && ((eq[j2] >> lane) & 1ull)) { sel[j2] |= 1ull << lane; --r; }
                }
            }
        }
    }
}

// Quad top-16 bisection: all 4 wave rows searched in lockstep — 32 ballots
// in flight per probe; wall time ~= max over rows instead of sum.
__device__ __forceinline__ void select16_quad(
    const unsigned u[4][8], unsigned long long sel[4][8],
    const unsigned* lo0, const unsigned* hi0)
{
    unsigned lo[4], hi[4];
    bool done[4];
    {
        unsigned long long mm[4][8];
        int cnt[4];
        #pragma unroll
        for (int r = 0; r < 4; ++r) {
            cnt[r] = 0;
            #pragma unroll
            for (int j = 0; j < 8; ++j) { mm[r][j] = __ballot(u[r][j] > lo0[r]); cnt[r] += __popcll(mm[r][j]); }
        }
        #pragma unroll
        for (int r = 0; r < 4; ++r) {
            done[r] = (cnt[r] == 16);
            if (done[r]) copy8(sel[r], mm[r]);
            lo[r] = (cnt[r] < 16) ? 0u : lo0[r];   // ordkey(finite) > 0 => cnt(>0)=512>16
            hi[r] = hi0[r];
        }
    }
    while ((!done[0] && hi[0] - lo[0] > 1u) || (!done[1] && hi[1] - lo[1] > 1u) ||
           (!done[2] && hi[2] - lo[2] > 1u) || (!done[3] && hi[3] - lo[3] > 1u)) {
        unsigned mid[4];
        unsigned long long mm[4][8];
        int cnt[4];
        #pragma unroll
        for (int r = 0; r < 4; ++r) mid[r] = lo[r] + ((hi[r] - lo[r]) >> 1);
        #pragma unroll
        for (int r = 0; r < 4; ++r) {
            cnt[r] = 0;
            #pragma unroll
            for (int j = 0; j < 8; ++j) { mm[r][j] = __ballot(u[r][j] > mid[r]); cnt[r] += __popcll(mm[r][j]); }
        }
        #pragma unroll
        for (int r = 0; r < 4; ++r) {
            if (!done[r] && hi[r] - lo[r] > 1u) {
                if (cnt[r] == 16) { copy8(sel[r], mm[r]); done[r] = true; }
                else if (cnt[r] > 16) lo[r] = mid[r];
                else hi[r] = mid[r];
            }
        }
    }
    #pragma unroll
    for (int r = 0; r < 4; ++r)
        if (!done[r]) tie_fill(u[r], sel[r], hi[r]);
}

// ---------------------------------------------------------------------------
// Fused prep: blocks [0,4608) convert weights; blocks [4608,8704) compute eo
// ---------------------------------------------------------------------------
__global__ __launch_bounds__(256) void prep_kernel(
    const float* __restrict__ q_w, const float* __restrict__ k_w,
    const float* __restrict__ v_w, const float* __restrict__ out_w,
    const float* __restrict__ emb,
    const float* __restrict__ adaln_w, const float* __restrict__ adaln_b,
    const float* __restrict__ xfn_w,  const float* __restrict__ xfn_b,
    _Float16* __restrict__ qwh, _Float16* __restrict__ qwl,
    _Float16* __restrict__ kwh, _Float16* __restrict__ kwl,
    _Float16* __restrict__ vw16, _Float16* __restrict__ ow16,
    float* __restrict__ eo)
{
    if (blockIdx.x < 4608) {
        int idx = blockIdx.x * 256 + threadIdx.x;
        if (idx < 442368) {
            float x = q_w[idx];
            _Float16 hi = (_Float16)x;
            qwh[idx] = hi; qwl[idx] = (_Float16)(x - (float)hi);
        } else if (idx < 442368 + 147456) {
            int i = idx - 442368;
            float x = k_w[i];
            _Float16 hi = (_Float16)x;
            kwh[i] = hi; kwl[i] = (_Float16)(x - (float)hi);
        } else if (idx < 442368 + 294912) {
            int i = idx - 442368 - 147456;
            vw16[i] = (_Float16)v_w[i];
        } else {
            int i = idx - 442368 - 294912;
            ow16[i] = (_Float16)out_w[i];
        }
    } else {
        int wid  = (blockIdx.x - 4608) * 4 + (threadIdx.x >> 6);
        int lane = threadIdx.x & 63;
        int l = wid >> 12;
        int rem = wid & 4095;
        int b = rem >> 10;
        int o = rem & 1023;
        const float* wrow = (l < 3) ? (adaln_w + ((size_t)(l * 1024 + o)) * 512)
                                    : (xfn_w + (size_t)o * 512);
        const float* erow = emb + b * 512;
        float acc = 0.f;
        for (int d = lane; d < 512; d += 64) {
            float e = erow[d];
            float se = e / (1.f + __expf(-e));
            acc = fmaf(se, wrow[d], acc);
        }
        #pragma unroll
        for (int off = 32; off; off >>= 1) acc += __shfl_xor(acc, off, 64);
        if (lane == 0) {
            float bias = (l < 3) ? adaln_b[l * 1024 + o] : xfn_b[o];
            eo[wid] = acc + bias;
        }
    }
}

// ---------------------------------------------------------------------------
// LayerNorm + modulation -> fp16 hi+lo planes
// ---------------------------------------------------------------------------
__global__ __launch_bounds__(256) void ln_kernel(
    const float* __restrict__ x1, const float* __restrict__ x2,
    const float* __restrict__ x3, const float* __restrict__ xf,
    const float* __restrict__ eo,
    _Float16* __restrict__ xnqh, _Float16* __restrict__ xnql,
    _Float16* __restrict__ xfnh, _Float16* __restrict__ xfnl)
{
    int row = blockIdx.x;
    const float* src; const float* eorow; _Float16* dh; _Float16* dl;
    if (row < 6144) {
        int l = row >> 11, idx = row & 2047, b = idx >> 9;
        const float* xp = (l == 0) ? x1 : (l == 1) ? x2 : x3;
        src = xp + (size_t)idx * 512;
        eorow = eo + (size_t)(l * 4 + b) * 1024;
        dh = xnqh + (size_t)row * 512;
        dl = xnql + (size_t)row * 512;
    } else {
        int rr = row - 6144; int b = rr >> 12;
        src = xf + (size_t)rr * 512;
        eorow = eo + (size_t)(12 + b) * 1024;
        dh = xfnh + (size_t)rr * 512;
        dl = xfnl + (size_t)rr * 512;
    }
    int tid = threadIdx.x;
    float2 vv = *(const float2*)(src + 2 * tid);
    float s = vv.x + vv.y;
    float q = fmaf(vv.x, vv.x, vv.y * vv.y);
    #pragma unroll
    for (int off = 32; off; off >>= 1) {
        s += __shfl_xor(s, off, 64);
        q += __shfl_xor(q, off, 64);
    }
    __shared__ float red[8];
    int wv = tid >> 6, lane = tid & 63;
    if (lane == 0) { red[wv] = s; red[4 + wv] = q; }
    __syncthreads();
    s = red[0] + red[1] + red[2] + red[3];
    q = red[4] + red[5] + red[6] + red[7];
    float mu  = s * (1.f / 512.f);
    float var = q * (1.f / 512.f) - mu * mu;
    float rs  = 1.f / sqrtf(var + 1e-6f);
    float2 sc = *(const float2*)(eorow + 2 * tid);
    float2 sh = *(const float2*)(eorow + 512 + 2 * tid);
    float r0 = (vv.x - mu) * rs * (1.f + sc.x) + sh.x;
    float r1 = (vv.y - mu) * rs * (1.f + sc.y) + sh.y;
    _Float16 h0 = (_Float16)r0, h1 = (_Float16)r1;
    half2v H = {h0, h1};
    half2v L = {(_Float16)(r0 - (float)h0), (_Float16)(r1 - (float)h1)};
    *(half2v*)(dh + 2 * tid) = H;
    *(half2v*)(dl + 2 * tid) = L;
}

// ---------------------------------------------------------------------------
// fp16 MFMA GEMM, LDS-free, per-wave 16 x (NF*16) tile (MF=1 for 2x waves).
// MODE 0: Q-proj  SPLIT  -> Qb [bh][1536][36]
// MODE 1: K-proj  SPLIT  -> Kt [bh][36][512] (transposed)
// MODE 2: V-proj  single -> Vb [bh][512][36]
// MODE 3: out-proj single (att16 [b][1536][288], A-rows remapped) -> d_out
// SPLIT: acc = Ah@Wh + Ah@Wl + Al@Wh
// ---------------------------------------------------------------------------
template<int NF, int MODE>
__global__ __launch_bounds__(256) void gemm16_kernel(
    const _Float16* __restrict__ Ah, const _Float16* __restrict__ Al,
    const _Float16* __restrict__ Wh, const _Float16* __restrict__ Wl,
    const float* __restrict__ bias,
    float* __restrict__ O0)
{
    constexpr bool SPLIT = (MODE == 0 || MODE == 1);
    const int Kd = (MODE == 3) ? 288 : 512;
    const int NT = (MODE == 0) ? 6 : (MODE == 3) ? 8 : 1;
    const int gw = blockIdx.x * 4 + (threadIdx.x >> 6);
    const int l  = threadIdx.x & 63;
    const int mt = gw / NT, nt = gw - mt * NT;
    const int row0 = mt * 16;
    const int col0 = nt * (NF * 16);
    const int lr = l & 15, lk = (l >> 4) * 8;

    int lsel = 0, h = 0;
    if (MODE == 0)                   { lsel = row0 >> 11; }
    else if (MODE == 1 || MODE == 2) { h = (row0 >> 9) & 7; }
    else                             { lsel = row0 >> 11; }

    size_t arow0;
    if (MODE == 3) {
        int rb = row0 & 2047, bb = rb >> 9, t0 = rb & 511;
        arow0 = (size_t)bb * 1536 + (size_t)lsel * 512 + t0;
    } else {
        arow0 = (size_t)row0;
    }

    const _Float16* aph = Ah + (arow0 + lr) * Kd + lk;
    const _Float16* apl = SPLIT ? (Al + (arow0 + lr) * Kd + lk) : nullptr;

    const _Float16* bph[NF];
    const _Float16* bpl[NF];
    #pragma unroll
    for (int f = 0; f < NF; ++f) {
        int c = col0 + f * 16 + lr;
        int wr;
        if (MODE == 0)      wr = lsel * 288 + c;
        else if (MODE == 3) wr = lsel * 512 + c;
        else                wr = h * 36 + (c < 36 ? c : 0);   // clamp; write masked
        bph[f] = Wh + (size_t)wr * Kd + lk;
        if (SPLIT) bpl[f] = Wl + (size_t)wr * Kd + lk;
    }

    f32x4 acc[NF];
    #pragma unroll
    for (int f = 0; f < NF; ++f) acc[f] = (f32x4){0.f, 0.f, 0.f, 0.f};

    #pragma unroll 2
    for (int kk = 0; kk < Kd; kk += 32) {
        half8 a0h = *(const half8*)(aph + kk);
        half8 a0l;
        if constexpr (SPLIT) a0l = *(const half8*)(apl + kk);
        #pragma unroll
        for (int f = 0; f < NF; ++f) {
            half8 bh_ = *(const half8*)(bph[f] + kk);
            acc[f] = __builtin_amdgcn_mfma_f32_16x16x32_f16(a0h, bh_, acc[f], 0, 0, 0);
            if constexpr (SPLIT) {
                half8 bl_ = *(const half8*)(bpl[f] + kk);
                acc[f] = __builtin_amdgcn_mfma_f32_16x16x32_f16(a0h, bl_, acc[f], 0, 0, 0);
                acc[f] = __builtin_amdgcn_mfma_f32_16x16x32_f16(a0l, bh_, acc[f], 0, 0, 0);
            }
        }
    }

    // epilogue: D row = (l>>4)*4 + j, col = l&15
    int rbase = row0 + (l >> 4) * 4;
    #pragma unroll
    for (int f = 0; f < NF; ++f) {
        int c = col0 + f * 16 + (l & 15);
        if (MODE == 0) {
            int hh = c / 36, hd = c - hh * 36;
            float bz = bias[lsel * 288 + c];
            #pragma unroll
            for (int j = 0; j < 4; ++j) {
                int r = rbase + j;
                int rb = r & 2047, bb2 = rb >> 9, t = rb & 511;
                O0[(((size_t)bb2 * 8 + hh) * 1536 + lsel * 512 + t) * 36 + hd]
                    = acc[f][j] + bz;
            }
        } else if (MODE == 1) {
            if (c < 36) {
                int bb2 = row0 >> 12;
                int n0 = rbase & 511;
                float bz = bias[h * 36 + c];
                float4 v4;
                v4.x = acc[f][0] + bz; v4.y = acc[f][1] + bz;
                v4.z = acc[f][2] + bz; v4.w = acc[f][3] + bz;
                *(float4*)&O0[(((size_t)bb2 * 8 + h) * 36 + c) * 512 + n0] = v4;
            }
        } else if (MODE == 2) {
            if (c < 36) {
                int bb2 = row0 >> 12;
                int n0 = rbase & 511;
                float bz = bias[h * 36 + c];
                #pragma unroll
                for (int j = 0; j < 4; ++j)
                    O0[(((size_t)bb2 * 8 + h) * 512 + n0 + j) * 36 + c]
                        = acc[f][j] + bz;
            }
        } else {
            float bz = bias[lsel * 512 + c];
            #pragma unroll
            for (int j = 0; j < 4; ++j) {
                int r = rbase + j;
                int rb = r & 2047, bb2 = rb >> 9, t = rb & 511;
                O0[(size_t)lsel * 1048576 + ((size_t)bb2 * 512 + t) * 512 + c]
                    = acc[f][j] + bz;
            }
        }
    }
}

// ---------------------------------------------------------------------------
// Attention: 1536 blocks XCD-swizzled. u_noise batched AFTER QK (8 loads in
// flight, no early L2 pollution — R9 lesson); all 4 wave rows selected in one
// quad-lockstep bisection; exp+sum fused into ballot-rank compaction; fixed
// 16-iter PV gather per row-pair. Writes att16 fp16 [b][1536][288].
// ---------------------------------------------------------------------------
__global__ __launch_bounds__(512, 3) void attn_kernel(
    const float* __restrict__ Qb, const float* __restrict__ Kt,
    const float* __restrict__ Vb, const float* __restrict__ un,
    _Float16* __restrict__ att16)
{
    __shared__ float Q_s[36 * 32];
    __shared__ float CmpW[8][4][16];
    __shared__ int   CmpN[8][4][16];

    const int tid = threadIdx.x;
    // XCD swizzle: 1536 % 8 == 0 -> bijective; same-bh chunks share an XCD L2
    const int bid = ((int)blockIdx.x & 7) * 192 + ((int)blockIdx.x >> 3);
    const int bh = bid / 48;
    const int chunk = bid - bh * 48;
    const int t0p = chunk * 32;
    const int b = bh >> 3, h = bh & 7;
    const int l = tid & 63;
    const int wv = tid >> 6;
    const int w4 = wv * 4;
    const int dpv = l & 31, halfw = l >> 5;
    const float S6 = 1.0f / 6.0f;

    for (int idx = tid; idx < 32 * 36; idx += 512) {
        int r = idx & 31, dd = idx >> 5;
        Q_s[dd * 32 + r] = Qb[((size_t)bh * 1536 + t0p + r) * 36 + dd];
    }
    __syncthreads();

    const float* Ktbh = Kt + (size_t)bh * 18432;
    const float* Vbh  = Vb + (size_t)bh * 18432;

    // QK^T: acc[4 rows][8 slots], slot j -> n = (j>>2)*256 + l*4 + (j&3)
    float acc[4][8];
    #pragma unroll
    for (int r = 0; r < 4; ++r)
        #pragma unroll
        for (int j = 0; j < 8; ++j) acc[r][j] = 0.f;

    #pragma unroll 6
    for (int dd = 0; dd < 36; ++dd) {
        float4 q   = FI4(&Q_s[dd * 32 + w4]);
        const float* ktr = Ktbh + dd * 512;
        float4 ka  = FI4(&ktr[l * 4]);
        float4 kb2 = FI4(&ktr[256 + l * 4]);
        float qv[4] = {q.x, q.y, q.z, q.w};
        float kv[8] = {ka.x, ka.y, ka.z, ka.w, kb2.x, kb2.y, kb2.z, kb2.w};
        #pragma unroll
        for (int r = 0; r < 4; ++r)
            #pragma unroll
            for (int j = 0; j < 8; ++j)
                acc[r][j] = fmaf(qv[r], kv[j], acc[r][j]);
    }

    // batched u loads (after QK — 8 loads in flight, latencies overlap)
    float4 ub[4][2];
    {
        const float* ubase = un + ((size_t)bh * 1536 + t0p + w4) * 512;
        #pragma unroll
        for (int r = 0; r < 4; ++r) {
            ub[r][0] = FI4(&ubase[(size_t)r * 512 + l * 4]);
            ub[r][1] = FI4(&ubase[(size_t)r * 512 + 256 + l * 4]);
        }
    }

    // logits (in place) + keys + per-row max
    unsigned key[4][8];
    float m[4];
    unsigned lo0[4], hi0[4];
    #pragma unroll
    for (int r = 0; r < 4; ++r) {
        acc[r][0] = fmaf(acc[r][0], S6, gumbelf(ub[r][0].x));
        acc[r][1] = fmaf(acc[r][1], S6, gumbelf(ub[r][0].y));
        acc[r][2] = fmaf(acc[r][2], S6, gumbelf(ub[r][0].z));
        acc[r][3] = fmaf(acc[r][3], S6, gumbelf(ub[r][0].w));
        acc[r][4] = fmaf(acc[r][4], S6, gumbelf(ub[r][1].x));
        acc[r][5] = fmaf(acc[r][5], S6, gumbelf(ub[r][1].y));
        acc[r][6] = fmaf(acc[r][6], S6, gumbelf(ub[r][1].z));
        acc[r][7] = fmaf(acc[r][7], S6, gumbelf(ub[r][1].w));
        float mr = acc[r][0];
        #pragma unroll
        for (int j = 0; j < 8; ++j) {
            key[r][j] = ordkey(acc[r][j]);
            mr = fmaxf(mr, acc[r][j]);
        }
        m[r] = wave_max_bcast(mr);
        lo0[r] = ordkey(m[r] - 28.0f);
        hi0[r] = ordkey(m[r]);
    }

    unsigned long long sel[4][8];
    select16_quad(key, sel, lo0, hi0);

    // exp + sum + ballot-rank compaction, fused (no e[4][8] array)
    float sum[4];
    #pragma unroll
    for (int r = 0; r < 4; ++r) {
        int base = 0;
        float ps = 0.f;
        #pragma unroll
        for (int j = 0; j < 8; ++j) {
            unsigned long long mk = sel[r][j];
            if ((mk >> l) & 1ull) {
                float ex = __expf(acc[r][j] - m[r]);
                ps += ex;
                int rank = base + mbcnt64(mk);
                CmpN[wv][r][rank] = ((j >> 2) << 8) + l * 4 + (j & 3);
                CmpW[wv][r][rank] = ex;
            }
            base += __popcll(mk);
        }
        sum[r] = wave_sum_bcast(ps);
    }
    asm volatile("s_waitcnt lgkmcnt(0)" ::: "memory");

    // PV gathers: half-wave 0 -> row 2pr, half-wave 1 -> row 2pr+1
    #pragma unroll
    for (int pr = 0; pr < 2; ++pr) {
        const int row = pr * 2 + halfw;
        float od = 0.f, od2 = 0.f;
        #pragma unroll
        for (int k = 0; k < 16; ++k) {
            int nn  = CmpN[wv][row][k];
            float w = CmpW[wv][row][k];
            const float* vr = Vbh + (size_t)nn * 36;
            od = fmaf(w, vr[dpv], od);
            if (dpv < 4) od2 = fmaf(w, vr[32 + dpv], od2);
        }
        float invs = 1.0f / sum[row];
        int t = t0p + w4 + row;
        _Float16* orow = att16 + ((size_t)b * 1536 + t) * 288 + h * 36;
        orow[dpv] = (_Float16)(od * invs);
        if (dpv < 4) orow[32 + dpv] = (_Float16)(od2 * invs);
    }
}

// ---------------------------------------------------------------------------
extern "C" void kernel_launch(void* const* d_in, const int* in_sizes, int n_in,
                              void* d_out, int out_size, void* d_ws, size_t ws_size,
                              hipStream_t stream)
{
    (void)in_sizes; (void)n_in; (void)out_size; (void)ws_size;
    const float* x1      = (const float*)d_in[0];
    const float* x2      = (const float*)d_in[1];
    const float* x3      = (const float*)d_in[2];
    const float* xf      = (const float*)d_in[3];
    const float* emb     = (const float*)d_in[4];
    const float* un      = (const float*)d_in[5];
    const float* adaln_w = (const float*)d_in[6];
    const float* adaln_b = (const float*)d_in[7];
    const float* xfn_w   = (const float*)d_in[8];
    const float* xfn_b   = (const float*)d_in[9];
    const float* q_w     = (const float*)d_in[10];
    const float* q_b     = (const float*)d_in[11];
    const float* k_w     = (const float*)d_in[12];
    const float* k_b     = (const float*)d_in[13];
    const float* v_w     = (const float*)d_in[14];
    const float* v_b     = (const float*)d_in[15];
    const float* out_w   = (const float*)d_in[16];
    const float* out_b   = (const float*)d_in[17];
    float* out = (float*)d_out;

    float* ws = (float*)d_ws;
    float* eo = ws;                          // 16,384 f32
    float* Qb = eo + 16384;                  // 1,769,472 f32
    float* Kt = Qb + 1769472;                // 589,824 f32  [bh][36][512]
    float* Vb = Kt + 589824;                 // 589,824 f32  [bh][512][36]
    _Float16* xnqh = (_Float16*)(Vb + 589824);   // 3,145,728 h
    _Float16* xnql = xnqh + 3145728;
    _Float16* xfnh = xnql + 3145728;         // 8,388,608 h
    _Float16* xfnl = xfnh + 8388608;
    _Float16* att16 = xfnl + 8388608;        // 1,769,472 h
    _Float16* qwh  = att16 + 1769472;        // 442,368 h
    _Float16* qwl  = qwh + 442368;
    _Float16* kwh  = qwl + 442368;           // 147,456 h
    _Float16* kwl  = kwh + 147456;
    _Float16* vw16 = kwl + 147456;           // 147,456 h
    _Float16* ow16 = vw16 + 147456;          // 442,368 h

    prep_kernel<<<8704, 256, 0, stream>>>(q_w, k_w, v_w, out_w, emb,
                                          adaln_w, adaln_b, xfn_w, xfn_b,
                                          qwh, qwl, kwh, kwl, vw16, ow16, eo);
    ln_kernel<<<22528, 256, 0, stream>>>(x1, x2, x3, xf, eo, xnqh, xnql, xfnh, xfnl);
    gemm16_kernel<3, 0><<<576, 256, 0, stream>>>(xnqh, xnql, qwh, qwl, q_b, Qb);
    gemm16_kernel<3, 1><<<256, 256, 0, stream>>>(xfnh, xfnl, kwh, kwl, k_b, Kt);
    gemm16_kernel<3, 2><<<256, 256, 0, stream>>>(xfnh, nullptr, vw16, nullptr, v_b, Vb);
    attn_kernel<<<1536, 512, 0, stream>>>(Qb, Kt, Vb, un, att16);
    gemm16_kernel<4, 3><<<768, 256, 0, stream>>>(att16, nullptr, ow16, nullptr, out_b, out);
}

// Round 13
// 183.934 us; speedup vs baseline: 1.3286x; 1.3286x over previous
//
#include <hip/hip_runtime.h>
#include <math.h>

#define FI4(p) (*(const float4*)(p))

typedef _Float16 half8 __attribute__((ext_vector_type(8)));
typedef _Float16 half2v __attribute__((ext_vector_type(2)));
typedef float f32x4 __attribute__((ext_vector_type(4)));

__device__ __forceinline__ float gumbelf(float u) {
    return -__logf(-__logf(u + 1e-9f) + 1e-9f);
}

template<int CTRL>
__device__ __forceinline__ int dppmov(int v) {
    return __builtin_amdgcn_update_dpp(v, v, CTRL, 0xF, 0xF, false);
}
__device__ __forceinline__ float wave_max_bcast(float v) {
    v = fmaxf(v, __int_as_float(dppmov<0xB1>(__float_as_int(v))));
    v = fmaxf(v, __int_as_float(dppmov<0x4E>(__float_as_int(v))));
    v = fmaxf(v, __int_as_float(dppmov<0x141>(__float_as_int(v))));
    v = fmaxf(v, __int_as_float(dppmov<0x140>(__float_as_int(v))));
    v = fmaxf(v, __int_as_float(dppmov<0x142>(__float_as_int(v))));
    v = fmaxf(v, __int_as_float(dppmov<0x143>(__float_as_int(v))));
    return __int_as_float(__builtin_amdgcn_readlane(__float_as_int(v), 63));
}
__device__ __forceinline__ float wave_sum_bcast(float v) {
    v += __int_as_float(dppmov<0xB1>(__float_as_int(v)));
    v += __int_as_float(dppmov<0x4E>(__float_as_int(v)));
    v += __int_as_float(dppmov<0x141>(__float_as_int(v)));
    v += __int_as_float(dppmov<0x140>(__float_as_int(v)));
    v += __int_as_float(dppmov<0x142>(__float_as_int(v)));
    v += __int_as_float(dppmov<0x143>(__float_as_int(v)));
    return __int_as_float(__builtin_amdgcn_readlane(__float_as_int(v), 63));
}

__device__ __forceinline__ unsigned ordkey(float f) {
    unsigned x = __float_as_uint(f);
    return x ^ ((unsigned)((int)x >> 31) | 0x80000000u);
}

__device__ __forceinline__ int mbcnt64(unsigned long long m) {
    return __builtin_amdgcn_mbcnt_hi((unsigned)(m >> 32),
           __builtin_amdgcn_mbcnt_lo((unsigned)m, 0));
}

__device__ __forceinline__ void copy8(unsigned long long* dst, const unsigned long long* src) {
    #pragma unroll
    for (int j = 0; j < 8; ++j) dst[j] = src[j];
}

// ties at key == hi filled by smallest n; n = (j>>2)*256 + lane*4 + (j&3)
__device__ __forceinline__ void tie_fill(const unsigned* u, unsigned long long* sel, unsigned hi)
{
    unsigned long long eq[8];
    int mcnt = 0;
    #pragma unroll
    for (int j = 0; j < 8; ++j) {
        sel[j] = __ballot(u[j] > hi);
        eq[j]  = __ballot(u[j] == hi);
        mcnt += __popcll(sel[j]);
    }
    int r = 16 - mcnt;
    #pragma unroll
    for (int jhi = 0; jhi < 2; ++jhi) {
        if (r > 0) {
            unsigned long long any = eq[jhi*4] | eq[jhi*4+1] | eq[jhi*4+2] | eq[jhi*4+3];
            while (any && r > 0) {
                int lane = (int)__builtin_ctzll(any); any &= any - 1;
                #pragma unroll
                for (int jlo = 0; jlo < 4; ++jlo) {
                    int j2 = jhi * 4 + jlo;
                    if (r > 0 && ((eq[j2] >> lane) & 1ull)) { sel[j2] |= 1ull << lane; --r; }
                }
            }
        }
    }
}

// Dual top-16 bisection: rows A and B searched in lockstep so the two
// dependent ballot->popcount->branch chains overlap (16 ballots in flight).
__device__ __forceinline__ void select16_pair(
    const unsigned* uA, const unsigned* uB,
    unsigned long long* selA, unsigned long long* selB,
    unsigned loA, unsigned hiA, unsigned loB, unsigned hiB)
{
    bool doneA = false, doneB = false;
    {
        unsigned long long mmA[8], mmB[8];
        int cA = 0, cB = 0;
        #pragma unroll
        for (int j = 0; j < 8; ++j) {
            mmA[j] = __ballot(uA[j] > loA); cA += __popcll(mmA[j]);
            mmB[j] = __ballot(uB[j] > loB); cB += __popcll(mmB[j]);
        }
        if (cA == 16) { copy8(selA, mmA); doneA = true; }
        else if (cA < 16) loA = 0u;   // ordkey(finite) > 0 => cnt(>0) = 512 > 16
        if (cB == 16) { copy8(selB, mmB); doneB = true; }
        else if (cB < 16) loB = 0u;
    }
    while ((!doneA && hiA - loA > 1u) || (!doneB && hiB - loB > 1u)) {
        bool pA = !doneA && (hiA - loA > 1u);
        bool pB = !doneB && (hiB - loB > 1u);
        unsigned midA = loA + ((hiA - loA) >> 1);
        unsigned midB = loB + ((hiB - loB) >> 1);
        unsigned long long mmA[8], mmB[8];
        int cA = 0, cB = 0;
        #pragma unroll
        for (int j = 0; j < 8; ++j) {
            mmA[j] = __ballot(uA[j] > midA); cA += __popcll(mmA[j]);
            mmB[j] = __ballot(uB[j] > midB); cB += __popcll(mmB[j]);
        }
        if (pA) {
            if (cA == 16) { copy8(selA, mmA); doneA = true; }
            else if (cA > 16) loA = midA; else hiA = midA;
        }
        if (pB) {
            if (cB == 16) { copy8(selB, mmB); doneB = true; }
            else if (cB > 16) loB = midB; else hiB = midB;
        }
    }
    if (!doneA) tie_fill(uA, selA, hiA);
    if (!doneB) tie_fill(uB, selB, hiB);
}

// ---------------------------------------------------------------------------
// Fused prep: blocks [0,4608) convert weights; blocks [4608,8704) compute eo
// ---------------------------------------------------------------------------
__global__ __launch_bounds__(256) void prep_kernel(
    const float* __restrict__ q_w, const float* __restrict__ k_w,
    const float* __restrict__ v_w, const float* __restrict__ out_w,
    const float* __restrict__ emb,
    const float* __restrict__ adaln_w, const float* __restrict__ adaln_b,
    const float* __restrict__ xfn_w,  const float* __restrict__ xfn_b,
    _Float16* __restrict__ qwh, _Float16* __restrict__ qwl,
    _Float16* __restrict__ kwh, _Float16* __restrict__ kwl,
    _Float16* __restrict__ vw16, _Float16* __restrict__ ow16,
    float* __restrict__ eo)
{
    if (blockIdx.x < 4608) {
        int idx = blockIdx.x * 256 + threadIdx.x;
        if (idx < 442368) {
            float x = q_w[idx];
            _Float16 hi = (_Float16)x;
            qwh[idx] = hi; qwl[idx] = (_Float16)(x - (float)hi);
        } else if (idx < 442368 + 147456) {
            int i = idx - 442368;
            float x = k_w[i];
            _Float16 hi = (_Float16)x;
            kwh[i] = hi; kwl[i] = (_Float16)(x - (float)hi);
        } else if (idx < 442368 + 294912) {
            int i = idx - 442368 - 147456;
            vw16[i] = (_Float16)v_w[i];
        } else {
            int i = idx - 442368 - 294912;
            ow16[i] = (_Float16)out_w[i];
        }
    } else {
        int wid  = (blockIdx.x - 4608) * 4 + (threadIdx.x >> 6);
        int lane = threadIdx.x & 63;
        int l = wid >> 12;
        int rem = wid & 4095;
        int b = rem >> 10;
        int o = rem & 1023;
        const float* wrow = (l < 3) ? (adaln_w + ((size_t)(l * 1024 + o)) * 512)
                                    : (xfn_w + (size_t)o * 512);
        const float* erow = emb + b * 512;
        float acc = 0.f;
        for (int d = lane; d < 512; d += 64) {
            float e = erow[d];
            float se = e / (1.f + __expf(-e));
            acc = fmaf(se, wrow[d], acc);
        }
        #pragma unroll
        for (int off = 32; off; off >>= 1) acc += __shfl_xor(acc, off, 64);
        if (lane == 0) {
            float bias = (l < 3) ? adaln_b[l * 1024 + o] : xfn_b[o];
            eo[wid] = acc + bias;
        }
    }
}

// ---------------------------------------------------------------------------
// LayerNorm + modulation -> fp16 hi+lo planes
// ---------------------------------------------------------------------------
__global__ __launch_bounds__(256) void ln_kernel(
    const float* __restrict__ x1, const float* __restrict__ x2,
    const float* __restrict__ x3, const float* __restrict__ xf,
    const float* __restrict__ eo,
    _Float16* __restrict__ xnqh, _Float16* __restrict__ xnql,
    _Float16* __restrict__ xfnh, _Float16* __restrict__ xfnl)
{
    int row = blockIdx.x;
    const float* src; const float* eorow; _Float16* dh; _Float16* dl;
    if (row < 6144) {
        int l = row >> 11, idx = row & 2047, b = idx >> 9;
        const float* xp = (l == 0) ? x1 : (l == 1) ? x2 : x3;
        src = xp + (size_t)idx * 512;
        eorow = eo + (size_t)(l * 4 + b) * 1024;
        dh = xnqh + (size_t)row * 512;
        dl = xnql + (size_t)row * 512;
    } else {
        int rr = row - 6144; int b = rr >> 12;
        src = xf + (size_t)rr * 512;
        eorow = eo + (size_t)(12 + b) * 1024;
        dh = xfnh + (size_t)rr * 512;
        dl = xfnl + (size_t)rr * 512;
    }
    int tid = threadIdx.x;
    float2 vv = *(const float2*)(src + 2 * tid);
    float s = vv.x + vv.y;
    float q = fmaf(vv.x, vv.x, vv.y * vv.y);
    #pragma unroll
    for (int off = 32; off; off >>= 1) {
        s += __shfl_xor(s, off, 64);
        q += __shfl_xor(q, off, 64);
    }
    __shared__ float red[8];
    int wv = tid >> 6, lane = tid & 63;
    if (lane == 0) { red[wv] = s; red[4 + wv] = q; }
    __syncthreads();
    s = red[0] + red[1] + red[2] + red[3];
    q = red[4] + red[5] + red[6] + red[7];
    float mu  = s * (1.f / 512.f);
    float var = q * (1.f / 512.f) - mu * mu;
    float rs  = 1.f / sqrtf(var + 1e-6f);
    float2 sc = *(const float2*)(eorow + 2 * tid);
    float2 sh = *(const float2*)(eorow + 512 + 2 * tid);
    float r0 = (vv.x - mu) * rs * (1.f + sc.x) + sh.x;
    float r1 = (vv.y - mu) * rs * (1.f + sc.y) + sh.y;
    _Float16 h0 = (_Float16)r0, h1 = (_Float16)r1;
    half2v H = {h0, h1};
    half2v L = {(_Float16)(r0 - (float)h0), (_Float16)(r1 - (float)h1)};
    *(half2v*)(dh + 2 * tid) = H;
    *(half2v*)(dl + 2 * tid) = L;
}

// ---------------------------------------------------------------------------
// fp16 MFMA GEMM body, LDS-free, per-wave 32 x (NF*16) tile (R10 config).
// MODE 0: Q-proj  SPLIT  -> Qb [bh][1536][36]
// MODE 1: K-proj  SPLIT  -> Kt [bh][36][512] (transposed)
// MODE 2: V-proj  single -> Vb [bh][512][36]
// MODE 3: out-proj single (att16 [b][1536][288], A-rows remapped) -> d_out
// SPLIT: acc = Ah@Wh + Ah@Wl + Al@Wh
// ---------------------------------------------------------------------------
template<int NF, int MODE>
__device__ __forceinline__ void gemm16_body(
    int gw, int l,
    const _Float16* __restrict__ Ah, const _Float16* __restrict__ Al,
    const _Float16* __restrict__ Wh, const _Float16* __restrict__ Wl,
    const float* __restrict__ bias,
    float* __restrict__ O0)
{
    constexpr bool SPLIT = (MODE == 0 || MODE == 1);
    const int Kd = (MODE == 3) ? 288 : 512;
    const int NT = (MODE == 0) ? 6 : (MODE == 3) ? 8 : 1;
    const int mt = gw / NT, nt = gw - mt * NT;
    const int row0 = mt * 32;
    const int col0 = nt * (NF * 16);
    const int lr = l & 15, lk = (l >> 4) * 8;

    int lsel = 0, h = 0;
    if (MODE == 0)                   { lsel = row0 >> 11; }
    else if (MODE == 1 || MODE == 2) { h = (row0 >> 9) & 7; }
    else                             { lsel = row0 >> 11; }

    size_t arow0;
    if (MODE == 3) {
        int rb = row0 & 2047, bb = rb >> 9, t0 = rb & 511;
        arow0 = (size_t)bb * 1536 + (size_t)lsel * 512 + t0;
    } else {
        arow0 = (size_t)row0;
    }

    const _Float16* aph = Ah + (arow0 + lr) * Kd + lk;
    const _Float16* apl = SPLIT ? (Al + (arow0 + lr) * Kd + lk) : nullptr;

    const _Float16* bph[NF];
    const _Float16* bpl[NF];
    #pragma unroll
    for (int f = 0; f < NF; ++f) {
        int c = col0 + f * 16 + lr;
        int wr;
        if (MODE == 0)      wr = lsel * 288 + c;
        else if (MODE == 3) wr = lsel * 512 + c;
        else                wr = h * 36 + (c < 36 ? c : 0);   // clamp; write masked
        bph[f] = Wh + (size_t)wr * Kd + lk;
        if (SPLIT) bpl[f] = Wl + (size_t)wr * Kd + lk;
    }

    f32x4 acc[2][NF];
    #pragma unroll
    for (int mi = 0; mi < 2; ++mi)
        #pragma unroll
        for (int f = 0; f < NF; ++f) acc[mi][f] = (f32x4){0.f, 0.f, 0.f, 0.f};

    for (int kk = 0; kk < Kd; kk += 32) {
        half8 a0h = *(const half8*)(aph + kk);
        half8 a1h = *(const half8*)(aph + (size_t)16 * Kd + kk);
        half8 a0l, a1l;
        if constexpr (SPLIT) {
            a0l = *(const half8*)(apl + kk);
            a1l = *(const half8*)(apl + (size_t)16 * Kd + kk);
        }
        #pragma unroll
        for (int f = 0; f < NF; ++f) {
            half8 bh_ = *(const half8*)(bph[f] + kk);
            acc[0][f] = __builtin_amdgcn_mfma_f32_16x16x32_f16(a0h, bh_, acc[0][f], 0, 0, 0);
            acc[1][f] = __builtin_amdgcn_mfma_f32_16x16x32_f16(a1h, bh_, acc[1][f], 0, 0, 0);
            if constexpr (SPLIT) {
                half8 bl_ = *(const half8*)(bpl[f] + kk);
                acc[0][f] = __builtin_amdgcn_mfma_f32_16x16x32_f16(a0h, bl_, acc[0][f], 0, 0, 0);
                acc[1][f] = __builtin_amdgcn_mfma_f32_16x16x32_f16(a1h, bl_, acc[1][f], 0, 0, 0);
                acc[0][f] = __builtin_amdgcn_mfma_f32_16x16x32_f16(a0l, bh_, acc[0][f], 0, 0, 0);
                acc[1][f] = __builtin_amdgcn_mfma_f32_16x16x32_f16(a1l, bh_, acc[1][f], 0, 0, 0);
            }
        }
    }

    #pragma unroll
    for (int mi = 0; mi < 2; ++mi) {
        int rbase = row0 + mi * 16 + (l >> 4) * 4;
        #pragma unroll
        for (int f = 0; f < NF; ++f) {
            int c = col0 + f * 16 + (l & 15);
            if (MODE == 0) {
                int hh = c / 36, hd = c - hh * 36;
                float bz = bias[lsel * 288 + c];
                #pragma unroll
                for (int j = 0; j < 4; ++j) {
                    int r = rbase + j;
                    int rb = r & 2047, bb2 = rb >> 9, t = rb & 511;
                    O0[(((size_t)bb2 * 8 + hh) * 1536 + lsel * 512 + t) * 36 + hd]
                        = acc[mi][f][j] + bz;
                }
            } else if (MODE == 1) {
                if (c < 36) {
                    int bb2 = row0 >> 12;
                    int n0 = rbase & 511;
                    float bz = bias[h * 36 + c];
                    float4 v4;
                    v4.x = acc[mi][f][0] + bz; v4.y = acc[mi][f][1] + bz;
                    v4.z = acc[mi][f][2] + bz; v4.w = acc[mi][f][3] + bz;
                    *(float4*)&O0[(((size_t)bb2 * 8 + h) * 36 + c) * 512 + n0] = v4;
                }
            } else if (MODE == 2) {
                if (c < 36) {
                    int bb2 = row0 >> 12;
                    int n0 = rbase & 511;
                    float bz = bias[h * 36 + c];
                    #pragma unroll
                    for (int j = 0; j < 4; ++j)
                        O0[(((size_t)bb2 * 8 + h) * 512 + n0 + j) * 36 + c]
                            = acc[mi][f][j] + bz;
                }
            } else {
                float bz = bias[lsel * 512 + c];
                #pragma unroll
                for (int j = 0; j < 4; ++j) {
                    int r = rbase + j;
                    int rb = r & 2047, bb2 = rb >> 9, t = rb & 511;
                    O0[(size_t)lsel * 1048576 + ((size_t)bb2 * 512 + t) * 512 + c]
                        = acc[mi][f][j] + bz;
                }
            }
        }
    }
}

// Fused Q/K/V projections: blocks [0,288) Q, [288,416) K, [416,544) V
__global__ __launch_bounds__(256) void qkv_kernel(
    const _Float16* __restrict__ xnqh, const _Float16* __restrict__ xnql,
    const _Float16* __restrict__ xfnh, const _Float16* __restrict__ xfnl,
    const _Float16* __restrict__ qwh,  const _Float16* __restrict__ qwl,
    const _Float16* __restrict__ kwh,  const _Float16* __restrict__ kwl,
    const _Float16* __restrict__ vw16,
    const float* __restrict__ q_b, const float* __restrict__ k_b,
    const float* __restrict__ v_b,
    float* __restrict__ Qb, float* __restrict__ Kt, float* __restrict__ Vb)
{
    const int l = threadIdx.x & 63;
    const int w = threadIdx.x >> 6;
    if (blockIdx.x < 288)
        gemm16_body<3, 0>(blockIdx.x * 4 + w, l, xnqh, xnql, qwh, qwl, q_b, Qb);
    else if (blockIdx.x < 416)
        gemm16_body<3, 1>((blockIdx.x - 288) * 4 + w, l, xfnh, xfnl, kwh, kwl, k_b, Kt);
    else
        gemm16_body<3, 2>((blockIdx.x - 416) * 4 + w, l, xfnh, nullptr, vw16, nullptr, v_b, Vb);
}

// out-proj standalone
__global__ __launch_bounds__(256) void outproj_kernel(
    const _Float16* __restrict__ att16, const _Float16* __restrict__ ow16,
    const float* __restrict__ out_b, float* __restrict__ out)
{
    const int l = threadIdx.x & 63;
    const int w = threadIdx.x >> 6;
    gemm16_body<4, 3>(blockIdx.x * 4 + w, l, att16, nullptr, ow16, nullptr, out_b, out);
}

// ---------------------------------------------------------------------------
// Attention: 1536 blocks XCD-swizzled (same-bh chunks share an XCD L2).
// u_noise batched AFTER QK (8 loads in flight, no early-L2 pollution);
// gumbel/keys/max for all 4 rows upfront; pair-select per pr (small arrays,
// no spill); ballot-rank compaction + fixed 16-iter PV gather.
// ---------------------------------------------------------------------------
__global__ __launch_bounds__(512, 4) void attn_kernel(
    const float* __restrict__ Qb, const float* __restrict__ Kt,
    const float* __restrict__ Vb, const float* __restrict__ un,
    _Float16* __restrict__ att16)
{
    __shared__ float Q_s[36 * 32];
    __shared__ float CmpW[8][2][2][16];
    __shared__ int   CmpN[8][2][2][16];

    const int tid = threadIdx.x;
    // XCD swizzle: 1536 % 8 == 0 -> bijective
    const int bid = ((int)blockIdx.x & 7) * 192 + ((int)blockIdx.x >> 3);
    const int bh = bid / 48;
    const int chunk = bid - bh * 48;
    const int t0p = chunk * 32;
    const int b = bh >> 3, h = bh & 7;
    const int l = tid & 63;
    const int wv = tid >> 6;
    const int w4 = wv * 4;
    const int dpv = l & 31, halfw = l >> 5;
    const float S6 = 1.0f / 6.0f;

    for (int idx = tid; idx < 32 * 36; idx += 512) {
        int r = idx & 31, dd = idx >> 5;
        Q_s[dd * 32 + r] = Qb[((size_t)bh * 1536 + t0p + r) * 36 + dd];
    }
    __syncthreads();

    const float* Ktbh = Kt + (size_t)bh * 18432;
    const float* Vbh  = Vb + (size_t)bh * 18432;

    // QK^T: acc[4 rows][8 slots], slot j -> n = (j>>2)*256 + l*4 + (j&3)
    float acc[4][8];
    #pragma unroll
    for (int r = 0; r < 4; ++r)
        #pragma unroll
        for (int j = 0; j < 8; ++j) acc[r][j] = 0.f;

    #pragma unroll 6
    for (int dd = 0; dd < 36; ++dd) {
        float4 q   = FI4(&Q_s[dd * 32 + w4]);
        const float* ktr = Ktbh + dd * 512;
        float4 ka  = FI4(&ktr[l * 4]);
        float4 kb2 = FI4(&ktr[256 + l * 4]);
        float qv[4] = {q.x, q.y, q.z, q.w};
        float kv[8] = {ka.x, ka.y, ka.z, ka.w, kb2.x, kb2.y, kb2.z, kb2.w};
        #pragma unroll
        for (int r = 0; r < 4; ++r)
            #pragma unroll
            for (int j = 0; j < 8; ++j)
                acc[r][j] = fmaf(qv[r], kv[j], acc[r][j]);
    }

    // batched u loads (after QK): 8 float4 in flight, latencies overlap
    float4 ub0[4], ub1[4];
    {
        const float* ubase = un + ((size_t)bh * 1536 + t0p + w4) * 512;
        #pragma unroll
        for (int r = 0; r < 4; ++r) {
            ub0[r] = FI4(&ubase[(size_t)r * 512 + l * 4]);
            ub1[r] = FI4(&ubase[(size_t)r * 512 + 256 + l * 4]);
        }
    }

    // logits in place + keys + per-row max (all 4 rows upfront)
    unsigned key[4][8];
    float m[4];
    #pragma unroll
    for (int r = 0; r < 4; ++r) {
        acc[r][0] = fmaf(acc[r][0], S6, gumbelf(ub0[r].x));
        acc[r][1] = fmaf(acc[r][1], S6, gumbelf(ub0[r].y));
        acc[r][2] = fmaf(acc[r][2], S6, gumbelf(ub0[r].z));
        acc[r][3] = fmaf(acc[r][3], S6, gumbelf(ub0[r].w));
        acc[r][4] = fmaf(acc[r][4], S6, gumbelf(ub1[r].x));
        acc[r][5] = fmaf(acc[r][5], S6, gumbelf(ub1[r].y));
        acc[r][6] = fmaf(acc[r][6], S6, gumbelf(ub1[r].z));
        acc[r][7] = fmaf(acc[r][7], S6, gumbelf(ub1[r].w));
        float mr = acc[r][0];
        #pragma unroll
        for (int j = 0; j < 8; ++j) {
            key[r][j] = ordkey(acc[r][j]);
            mr = fmaxf(mr, acc[r][j]);
        }
        m[r] = wave_max_bcast(mr);
    }

    #pragma unroll
    for (int pr = 0; pr < 2; ++pr) {
        const int rA = pr * 2, rB = pr * 2 + 1;

        unsigned long long selA[8], selB[8];
        select16_pair(key[rA], key[rB], selA, selB,
                      ordkey(m[rA] - 28.0f), ordkey(m[rA]),
                      ordkey(m[rB] - 28.0f), ordkey(m[rB]));

        // exp + sum + ballot-rank compaction
        float psA = 0.f, psB = 0.f;
        {
            int baseA = 0, baseB = 0;
            #pragma unroll
            for (int j = 0; j < 8; ++j) {
                unsigned long long ma = selA[j], mb = selB[j];
                int nj = ((j >> 2) << 8) + l * 4 + (j & 3);
                if ((ma >> l) & 1ull) {
                    float ex = __expf(acc[rA][j] - m[rA]);
                    psA += ex;
                    int rank = baseA + mbcnt64(ma);
                    CmpN[wv][pr][0][rank] = nj;
                    CmpW[wv][pr][0][rank] = ex;
                }
                if ((mb >> l) & 1ull) {
                    float ex = __expf(acc[rB][j] - m[rB]);
                    psB += ex;
                    int rank = baseB + mbcnt64(mb);
                    CmpN[wv][pr][1][rank] = nj;
                    CmpW[wv][pr][1][rank] = ex;
                }
                baseA += __popcll(ma); baseB += __popcll(mb);
            }
        }
        float sumA = wave_sum_bcast(psA);
        float sumB = wave_sum_bcast(psB);
        asm volatile("s_waitcnt lgkmcnt(0)" ::: "memory");

        // fixed 16-iter gather: independent V-row loads, full ILP
        float od = 0.f, od2 = 0.f;
        #pragma unroll
        for (int k = 0; k < 16; ++k) {
            int nn  = CmpN[wv][pr][halfw][k];
            float w = CmpW[wv][pr][halfw][k];
            const float* vr = Vbh + (size_t)nn * 36;
            od = fmaf(w, vr[dpv], od);
            if (dpv < 4) od2 = fmaf(w, vr[32 + dpv], od2);
        }

        float invs = 1.0f / (halfw ? sumB : sumA);
        int t = t0p + w4 + pr * 2 + halfw;
        _Float16* orow = att16 + ((size_t)b * 1536 + t) * 288 + h * 36;
        orow[dpv] = (_Float16)(od * invs);
        if (dpv < 4) orow[32 + dpv] = (_Float16)(od2 * invs);
    }
}

// ---------------------------------------------------------------------------
extern "C" void kernel_launch(void* const* d_in, const int* in_sizes, int n_in,
                              void* d_out, int out_size, void* d_ws, size_t ws_size,
                              hipStream_t stream)
{
    (void)in_sizes; (void)n_in; (void)out_size; (void)ws_size;
    const float* x1      = (const float*)d_in[0];
    const float* x2      = (const float*)d_in[1];
    const float* x3      = (const float*)d_in[2];
    const float* xf      = (const float*)d_in[3];
    const float* emb     = (const float*)d_in[4];
    const float* un      = (const float*)d_in[5];
    const float* adaln_w = (const float*)d_in[6];
    const float* adaln_b = (const float*)d_in[7];
    const float* xfn_w   = (const float*)d_in[8];
    const float* xfn_b   = (const float*)d_in[9];
    const float* q_w     = (const float*)d_in[10];
    const float* q_b     = (const float*)d_in[11];
    const float* k_w     = (const float*)d_in[12];
    const float* k_b     = (const float*)d_in[13];
    const float* v_w     = (const float*)d_in[14];
    const float* v_b     = (const float*)d_in[15];
    const float* out_w   = (const float*)d_in[16];
    const float* out_b   = (const float*)d_in[17];
    float* out = (float*)d_out;

    float* ws = (float*)d_ws;
    float* eo = ws;                          // 16,384 f32
    float* Qb = eo + 16384;                  // 1,769,472 f32
    float* Kt = Qb + 1769472;                // 589,824 f32  [bh][36][512]
    float* Vb = Kt + 589824;                 // 589,824 f32  [bh][512][36]
    _Float16* xnqh = (_Float16*)(Vb + 589824);   // 3,145,728 h
    _Float16* xnql = xnqh + 3145728;
    _Float16* xfnh = xnql + 3145728;         // 8,388,608 h
    _Float16* xfnl = xfnh + 8388608;
    _Float16* att16 = xfnl + 8388608;        // 1,769,472 h
    _Float16* qwh  = att16 + 1769472;        // 442,368 h
    _Float16* qwl  = qwh + 442368;
    _Float16* kwh  = qwl + 442368;           // 147,456 h
    _Float16* kwl  = kwh + 147456;
    _Float16* vw16 = kwl + 147456;           // 147,456 h
    _Float16* ow16 = vw16 + 147456;          // 442,368 h

    prep_kernel<<<8704, 256, 0, stream>>>(q_w, k_w, v_w, out_w, emb,
                                          adaln_w, adaln_b, xfn_w, xfn_b,
                                          qwh, qwl, kwh, kwl, vw16, ow16, eo);
    ln_kernel<<<22528, 256, 0, stream>>>(x1, x2, x3, xf, eo, xnqh, xnql, xfnh, xfnl);
    qkv_kernel<<<544, 256, 0, stream>>>(xnqh, xnql, xfnh, xfnl,
                                        qwh, qwl, kwh, kwl, vw16,
                                        q_b, k_b, v_b, Qb, Kt, Vb);
    attn_kernel<<<1536, 512, 0, stream>>>(Qb, Kt, Vb, un, att16);
    outproj_kernel<<<384, 256, 0, stream>>>(att16, ow16, out_b, out);
}

// Round 14
// 182.588 us; speedup vs baseline: 1.3384x; 1.0074x over previous
//
#include <hip/hip_runtime.h>
#include <math.h>

#define FI4(p) (*(const float4*)(p))

typedef _Float16 half8 __attribute__((ext_vector_type(8)));
typedef _Float16 half2v __attribute__((ext_vector_type(2)));
typedef float f32x4 __attribute__((ext_vector_type(4)));

__device__ __forceinline__ float gumbelf(float u) {
    return -__logf(-__logf(u + 1e-9f) + 1e-9f);
}

template<int CTRL>
__device__ __forceinline__ int dppmov(int v) {
    return __builtin_amdgcn_update_dpp(v, v, CTRL, 0xF, 0xF, false);
}
__device__ __forceinline__ float wave_max_bcast(float v) {
    v = fmaxf(v, __int_as_float(dppmov<0xB1>(__float_as_int(v))));
    v = fmaxf(v, __int_as_float(dppmov<0x4E>(__float_as_int(v))));
    v = fmaxf(v, __int_as_float(dppmov<0x141>(__float_as_int(v))));
    v = fmaxf(v, __int_as_float(dppmov<0x140>(__float_as_int(v))));
    v = fmaxf(v, __int_as_float(dppmov<0x142>(__float_as_int(v))));
    v = fmaxf(v, __int_as_float(dppmov<0x143>(__float_as_int(v))));
    return __int_as_float(__builtin_amdgcn_readlane(__float_as_int(v), 63));
}
__device__ __forceinline__ float wave_sum_bcast(float v) {
    v += __int_as_float(dppmov<0xB1>(__float_as_int(v)));
    v += __int_as_float(dppmov<0x4E>(__float_as_int(v)));
    v += __int_as_float(dppmov<0x141>(__float_as_int(v)));
    v += __int_as_float(dppmov<0x140>(__float_as_int(v)));
    v += __int_as_float(dppmov<0x142>(__float_as_int(v)));
    v += __int_as_float(dppmov<0x143>(__float_as_int(v)));
    return __int_as_float(__builtin_amdgcn_readlane(__float_as_int(v), 63));
}

__device__ __forceinline__ unsigned ordkey(float f) {
    unsigned x = __float_as_uint(f);
    return x ^ ((unsigned)((int)x >> 31) | 0x80000000u);
}

__device__ __forceinline__ int mbcnt64(unsigned long long m) {
    return __builtin_amdgcn_mbcnt_hi((unsigned)(m >> 32),
           __builtin_amdgcn_mbcnt_lo((unsigned)m, 0));
}

__device__ __forceinline__ void copy8(unsigned long long* dst, const unsigned long long* src) {
    #pragma unroll
    for (int j = 0; j < 8; ++j) dst[j] = src[j];
}

// ties at key == hi filled by smallest n; n = (j>>2)*256 + lane*4 + (j&3)
__device__ __forceinline__ void tie_fill(const unsigned* u, unsigned long long* sel, unsigned hi)
{
    unsigned long long eq[8];
    int mcnt = 0;
    #pragma unroll
    for (int j = 0; j < 8; ++j) {
        sel[j] = __ballot(u[j] > hi);
        eq[j]  = __ballot(u[j] == hi);
        mcnt += __popcll(sel[j]);
    }
    int r = 16 - mcnt;
    #pragma unroll
    for (int jhi = 0; jhi < 2; ++jhi) {
        if (r > 0) {
            unsigned long long any = eq[jhi*4] | eq[jhi*4+1] | eq[jhi*4+2] | eq[jhi*4+3];
            while (any && r > 0) {
                int lane = (int)__builtin_ctzll(any); any &= any - 1;
                #pragma unroll
                for (int jlo = 0; jlo < 4; ++jlo) {
                    int j2 = jhi * 4 + jlo;
                    if (r > 0 && ((eq[j2] >> lane) & 1ull)) { sel[j2] |= 1ull << lane; --r; }
                }
            }
        }
    }
}

// Dual top-16 bisection (rows A/B in lockstep; 16 ballots in flight / probe)
__device__ __forceinline__ void select16_pair(
    const unsigned* uA, const unsigned* uB,
    unsigned long long* selA, unsigned long long* selB,
    unsigned loA, unsigned hiA, unsigned loB, unsigned hiB)
{
    bool doneA = false, doneB = false;
    {
        unsigned long long mmA[8], mmB[8];
        int cA = 0, cB = 0;
        #pragma unroll
        for (int j = 0; j < 8; ++j) {
            mmA[j] = __ballot(uA[j] > loA); cA += __popcll(mmA[j]);
            mmB[j] = __ballot(uB[j] > loB); cB += __popcll(mmB[j]);
        }
        if (cA == 16) { copy8(selA, mmA); doneA = true; }
        else if (cA < 16) loA = 0u;   // fallback: full range (ordkey(finite) > 0)
        if (cB == 16) { copy8(selB, mmB); doneB = true; }
        else if (cB < 16) loB = 0u;
    }
    while ((!doneA && hiA - loA > 1u) || (!doneB && hiB - loB > 1u)) {
        bool pA = !doneA && (hiA - loA > 1u);
        bool pB = !doneB && (hiB - loB > 1u);
        unsigned midA = loA + ((hiA - loA) >> 1);
        unsigned midB = loB + ((hiB - loB) >> 1);
        unsigned long long mmA[8], mmB[8];
        int cA = 0, cB = 0;
        #pragma unroll
        for (int j = 0; j < 8; ++j) {
            mmA[j] = __ballot(uA[j] > midA); cA += __popcll(mmA[j]);
            mmB[j] = __ballot(uB[j] > midB); cB += __popcll(mmB[j]);
        }
        if (pA) {
            if (cA == 16) { copy8(selA, mmA); doneA = true; }
            else if (cA > 16) loA = midA; else hiA = midA;
        }
        if (pB) {
            if (cB == 16) { copy8(selB, mmB); doneB = true; }
            else if (cB > 16) loB = midB; else hiB = midB;
        }
    }
    if (!doneA) tie_fill(uA, selA, hiA);
    if (!doneB) tie_fill(uB, selB, hiB);
}

// ---------------------------------------------------------------------------
// Fused prep: [0,4608) weight convert; [4608,8704) eo; [8704,8960) zero d-pads
// of Qp/Kp rows (cols 36..40) so MFMA K-steps read zeros.
// ---------------------------------------------------------------------------
__global__ __launch_bounds__(256) void prep_kernel(
    const float* __restrict__ q_w, const float* __restrict__ k_w,
    const float* __restrict__ v_w, const float* __restrict__ out_w,
    const float* __restrict__ emb,
    const float* __restrict__ adaln_w, const float* __restrict__ adaln_b,
    const float* __restrict__ xfn_w,  const float* __restrict__ xfn_b,
    _Float16* __restrict__ qwh, _Float16* __restrict__ qwl,
    _Float16* __restrict__ kwh, _Float16* __restrict__ kwl,
    _Float16* __restrict__ vw16, _Float16* __restrict__ ow16,
    _Float16* __restrict__ Qph, _Float16* __restrict__ Qpl,
    _Float16* __restrict__ Kph, _Float16* __restrict__ Kpl,
    float* __restrict__ eo)
{
    if (blockIdx.x < 4608) {
        int idx = blockIdx.x * 256 + threadIdx.x;
        if (idx < 442368) {
            float x = q_w[idx];
            _Float16 hi = (_Float16)x;
            qwh[idx] = hi; qwl[idx] = (_Float16)(x - (float)hi);
        } else if (idx < 442368 + 147456) {
            int i = idx - 442368;
            float x = k_w[i];
            _Float16 hi = (_Float16)x;
            kwh[i] = hi; kwl[i] = (_Float16)(x - (float)hi);
        } else if (idx < 442368 + 294912) {
            int i = idx - 442368 - 147456;
            vw16[i] = (_Float16)v_w[i];
        } else {
            int i = idx - 442368 - 294912;
            ow16[i] = (_Float16)out_w[i];
        }
    } else if (blockIdx.x < 8704) {
        int wid  = (blockIdx.x - 4608) * 4 + (threadIdx.x >> 6);
        int lane = threadIdx.x & 63;
        int l = wid >> 12;
        int rem = wid & 4095;
        int b = rem >> 10;
        int o = rem & 1023;
        const float* wrow = (l < 3) ? (adaln_w + ((size_t)(l * 1024 + o)) * 512)
                                    : (xfn_w + (size_t)o * 512);
        const float* erow = emb + b * 512;
        float acc = 0.f;
        for (int d = lane; d < 512; d += 64) {
            float e = erow[d];
            float se = e / (1.f + __expf(-e));
            acc = fmaf(se, wrow[d], acc);
        }
        #pragma unroll
        for (int off = 32; off; off >>= 1) acc += __shfl_xor(acc, off, 64);
        if (lane == 0) {
            float bias = (l < 3) ? adaln_b[l * 1024 + o] : xfn_b[o];
            eo[wid] = acc + bias;
        }
    } else {
        int idx = (blockIdx.x - 8704) * 256 + threadIdx.x;   // < 65536
        short4 z = {0, 0, 0, 0};
        if (idx < 49152) {
            *(short4*)&Qph[(size_t)idx * 40 + 36] = z;
            *(short4*)&Qpl[(size_t)idx * 40 + 36] = z;
        } else {
            int i2 = idx - 49152;                             // < 16384
            *(short4*)&Kph[(size_t)i2 * 40 + 36] = z;
            *(short4*)&Kpl[(size_t)i2 * 40 + 36] = z;
        }
    }
}

// ---------------------------------------------------------------------------
// LayerNorm + modulation -> fp16 hi+lo planes
// ---------------------------------------------------------------------------
__global__ __launch_bounds__(256) void ln_kernel(
    const float* __restrict__ x1, const float* __restrict__ x2,
    const float* __restrict__ x3, const float* __restrict__ xf,
    const float* __restrict__ eo,
    _Float16* __restrict__ xnqh, _Float16* __restrict__ xnql,
    _Float16* __restrict__ xfnh, _Float16* __restrict__ xfnl)
{
    int row = blockIdx.x;
    const float* src; const float* eorow; _Float16* dh; _Float16* dl;
    if (row < 6144) {
        int l = row >> 11, idx = row & 2047, b = idx >> 9;
        const float* xp = (l == 0) ? x1 : (l == 1) ? x2 : x3;
        src = xp + (size_t)idx * 512;
        eorow = eo + (size_t)(l * 4 + b) * 1024;
        dh = xnqh + (size_t)row * 512;
        dl = xnql + (size_t)row * 512;
    } else {
        int rr = row - 6144; int b = rr >> 12;
        src = xf + (size_t)rr * 512;
        eorow = eo + (size_t)(12 + b) * 1024;
        dh = xfnh + (size_t)rr * 512;
        dl = xfnl + (size_t)rr * 512;
    }
    int tid = threadIdx.x;
    float2 vv = *(const float2*)(src + 2 * tid);
    float s = vv.x + vv.y;
    float q = fmaf(vv.x, vv.x, vv.y * vv.y);
    #pragma unroll
    for (int off = 32; off; off >>= 1) {
        s += __shfl_xor(s, off, 64);
        q += __shfl_xor(q, off, 64);
    }
    __shared__ float red[8];
    int wv = tid >> 6, lane = tid & 63;
    if (lane == 0) { red[wv] = s; red[4 + wv] = q; }
    __syncthreads();
    s = red[0] + red[1] + red[2] + red[3];
    q = red[4] + red[5] + red[6] + red[7];
    float mu  = s * (1.f / 512.f);
    float var = q * (1.f / 512.f) - mu * mu;
    float rs  = 1.f / sqrtf(var + 1e-6f);
    float2 sc = *(const float2*)(eorow + 2 * tid);
    float2 sh = *(const float2*)(eorow + 512 + 2 * tid);
    float r0 = (vv.x - mu) * rs * (1.f + sc.x) + sh.x;
    float r1 = (vv.y - mu) * rs * (1.f + sc.y) + sh.y;
    _Float16 h0 = (_Float16)r0, h1 = (_Float16)r1;
    half2v H = {h0, h1};
    half2v L = {(_Float16)(r0 - (float)h0), (_Float16)(r1 - (float)h1)};
    *(half2v*)(dh + 2 * tid) = H;
    *(half2v*)(dl + 2 * tid) = L;
}

// ---------------------------------------------------------------------------
// fp16 MFMA GEMM body, LDS-free, per-wave 32 x (NF*16) tile.
// MODE 0: Q-proj SPLIT  -> Qph/Qpl fp16 [bh*1536 rows][40] (d-pad zeros in prep)
// MODE 1: K-proj SPLIT  -> Kph/Kpl fp16 [bh*512 rows][40]
// MODE 2: V-proj single -> Vb f32 [bh][512][36]
// MODE 3: out-proj single (att16 [b][1536][288], A-rows remapped) -> d_out f32
// SPLIT: acc = Ah@Wh + Ah@Wl + Al@Wh
// ---------------------------------------------------------------------------
template<int NF, int MODE>
__device__ __forceinline__ void gemm16_body(
    int gw, int l,
    const _Float16* __restrict__ Ah, const _Float16* __restrict__ Al,
    const _Float16* __restrict__ Wh, const _Float16* __restrict__ Wl,
    const float* __restrict__ bias,
    float* __restrict__ Of, _Float16* __restrict__ Oh, _Float16* __restrict__ Ol)
{
    constexpr bool SPLIT = (MODE == 0 || MODE == 1);
    const int Kd = (MODE == 3) ? 288 : 512;
    const int NT = (MODE == 0) ? 6 : (MODE == 3) ? 8 : 1;
    const int mt = gw / NT, nt = gw - mt * NT;
    const int row0 = mt * 32;
    const int col0 = nt * (NF * 16);
    const int lr = l & 15, lk = (l >> 4) * 8;

    int lsel = 0, h = 0;
    if (MODE == 0)                   { lsel = row0 >> 11; }
    else if (MODE == 1 || MODE == 2) { h = (row0 >> 9) & 7; }
    else                             { lsel = row0 >> 11; }

    size_t arow0;
    if (MODE == 3) {
        int rb = row0 & 2047, bb = rb >> 9, t0 = rb & 511;
        arow0 = (size_t)bb * 1536 + (size_t)lsel * 512 + t0;
    } else {
        arow0 = (size_t)row0;
    }

    const _Float16* aph = Ah + (arow0 + lr) * Kd + lk;
    const _Float16* apl = SPLIT ? (Al + (arow0 + lr) * Kd + lk) : nullptr;

    const _Float16* bph[NF];
    const _Float16* bpl[NF];
    #pragma unroll
    for (int f = 0; f < NF; ++f) {
        int c = col0 + f * 16 + lr;
        int wr;
        if (MODE == 0)      wr = lsel * 288 + c;
        else if (MODE == 3) wr = lsel * 512 + c;
        else                wr = h * 36 + (c < 36 ? c : 0);   // clamp; write masked
        bph[f] = Wh + (size_t)wr * Kd + lk;
        if (SPLIT) bpl[f] = Wl + (size_t)wr * Kd + lk;
    }

    f32x4 acc[2][NF];
    #pragma unroll
    for (int mi = 0; mi < 2; ++mi)
        #pragma unroll
        for (int f = 0; f < NF; ++f) acc[mi][f] = (f32x4){0.f, 0.f, 0.f, 0.f};

    for (int kk = 0; kk < Kd; kk += 32) {
        half8 a0h = *(const half8*)(aph + kk);
        half8 a1h = *(const half8*)(aph + (size_t)16 * Kd + kk);
        half8 a0l, a1l;
        if constexpr (SPLIT) {
            a0l = *(const half8*)(apl + kk);
            a1l = *(const half8*)(apl + (size_t)16 * Kd + kk);
        }
        #pragma unroll
        for (int f = 0; f < NF; ++f) {
            half8 bh_ = *(const half8*)(bph[f] + kk);
            acc[0][f] = __builtin_amdgcn_mfma_f32_16x16x32_f16(a0h, bh_, acc[0][f], 0, 0, 0);
            acc[1][f] = __builtin_amdgcn_mfma_f32_16x16x32_f16(a1h, bh_, acc[1][f], 0, 0, 0);
            if constexpr (SPLIT) {
                half8 bl_ = *(const half8*)(bpl[f] + kk);
                acc[0][f] = __builtin_amdgcn_mfma_f32_16x16x32_f16(a0h, bl_, acc[0][f], 0, 0, 0);
                acc[1][f] = __builtin_amdgcn_mfma_f32_16x16x32_f16(a1h, bl_, acc[1][f], 0, 0, 0);
                acc[0][f] = __builtin_amdgcn_mfma_f32_16x16x32_f16(a0l, bh_, acc[0][f], 0, 0, 0);
                acc[1][f] = __builtin_amdgcn_mfma_f32_16x16x32_f16(a1l, bh_, acc[1][f], 0, 0, 0);
            }
        }
    }

    #pragma unroll
    for (int mi = 0; mi < 2; ++mi) {
        int rbase = row0 + mi * 16 + (l >> 4) * 4;
        #pragma unroll
        for (int f = 0; f < NF; ++f) {
            int c = col0 + f * 16 + (l & 15);
            if (MODE == 0) {
                int hh = c / 36, hd = c - hh * 36;
                float bz = bias[lsel * 288 + c];
                #pragma unroll
                for (int j = 0; j < 4; ++j) {
                    int r = rbase + j;
                    int rb = r & 2047, bb2 = rb >> 9, t = rb & 511;
                    size_t row = ((size_t)bb2 * 8 + hh) * 1536 + lsel * 512 + t;
                    float v = acc[mi][f][j] + bz;
                    _Float16 hi = (_Float16)v;
                    Oh[row * 40 + hd] = hi;
                    Ol[row * 40 + hd] = (_Float16)(v - (float)hi);
                }
            } else if (MODE == 1) {
                if (c < 36) {
                    int bb2 = row0 >> 12;
                    int n0 = rbase & 511;
                    float bz = bias[h * 36 + c];
                    #pragma unroll
                    for (int j = 0; j < 4; ++j) {
                        size_t row = ((size_t)bb2 * 8 + h) * 512 + n0 + j;
                        float v = acc[mi][f][j] + bz;
                        _Float16 hi = (_Float16)v;
                        Oh[row * 40 + c] = hi;
                        Ol[row * 40 + c] = (_Float16)(v - (float)hi);
                    }
                }
            } else if (MODE == 2) {
                if (c < 36) {
                    int bb2 = row0 >> 12;
                    int n0 = rbase & 511;
                    float bz = bias[h * 36 + c];
                    #pragma unroll
                    for (int j = 0; j < 4; ++j)
                        Of[(((size_t)bb2 * 8 + h) * 512 + n0 + j) * 36 + c]
                            = acc[mi][f][j] + bz;
                }
            } else {
                float bz = bias[lsel * 512 + c];
                #pragma unroll
                for (int j = 0; j < 4; ++j) {
                    int r = rbase + j;
                    int rb = r & 2047, bb2 = rb >> 9, t = rb & 511;
                    Of[(size_t)lsel * 1048576 + ((size_t)bb2 * 512 + t) * 512 + c]
                        = acc[mi][f][j] + bz;
                }
            }
        }
    }
}

// Fused Q/K/V projections: blocks [0,288) Q, [288,416) K, [416,544) V
__global__ __launch_bounds__(256) void qkv_kernel(
    const _Float16* __restrict__ xnqh, const _Float16* __restrict__ xnql,
    const _Float16* __restrict__ xfnh, const _Float16* __restrict__ xfnl,
    const _Float16* __restrict__ qwh,  const _Float16* __restrict__ qwl,
    const _Float16* __restrict__ kwh,  const _Float16* __restrict__ kwl,
    const _Float16* __restrict__ vw16,
    const float* __restrict__ q_b, const float* __restrict__ k_b,
    const float* __restrict__ v_b,
    _Float16* __restrict__ Qph, _Float16* __restrict__ Qpl,
    _Float16* __restrict__ Kph, _Float16* __restrict__ Kpl,
    float* __restrict__ Vb)
{
    const int l = threadIdx.x & 63;
    const int w = threadIdx.x >> 6;
    if (blockIdx.x < 288)
        gemm16_body<3, 0>(blockIdx.x * 4 + w, l, xnqh, xnql, qwh, qwl, q_b,
                          nullptr, Qph, Qpl);
    else if (blockIdx.x < 416)
        gemm16_body<3, 1>((blockIdx.x - 288) * 4 + w, l, xfnh, xfnl, kwh, kwl, k_b,
                          nullptr, Kph, Kpl);
    else
        gemm16_body<3, 2>((blockIdx.x - 416) * 4 + w, l, xfnh, nullptr, vw16, nullptr, v_b,
                          Vb, nullptr, nullptr);
}

// out-proj standalone
__global__ __launch_bounds__(256) void outproj_kernel(
    const _Float16* __restrict__ att16, const _Float16* __restrict__ ow16,
    const float* __restrict__ out_b, float* __restrict__ out)
{
    const int l = threadIdx.x & 63;
    const int w = threadIdx.x >> 6;
    gemm16_body<4, 3>(blockIdx.x * 4 + w, l, att16, nullptr, ow16, nullptr, out_b,
                      out, nullptr, nullptr);
}

// ---------------------------------------------------------------------------
// Attention: MFMA QK^T (split fp16, S^T per wave over 64 n-rows) -> S/6 into
// bank-padded LDS -> barrier -> R12 selection (pair bisect, seed m-8) +
// ballot-rank compaction + fixed 16-iter PV gather. XCD-swizzled grid.
// ---------------------------------------------------------------------------
__global__ __launch_bounds__(512, 2) void attn_kernel(
    const _Float16* __restrict__ Qph, const _Float16* __restrict__ Qpl,
    const _Float16* __restrict__ Kph, const _Float16* __restrict__ Kpl,
    const float* __restrict__ Vb, const float* __restrict__ un,
    _Float16* __restrict__ att16)
{
    __shared__ float S_lds[32 * 516];
    __shared__ float CmpW[8][2][2][16];
    __shared__ int   CmpN[8][2][2][16];

    const int tid = threadIdx.x;
    // XCD swizzle: 1536 % 8 == 0 -> bijective; same-bh chunks share an XCD L2
    const int bid = ((int)blockIdx.x & 7) * 192 + ((int)blockIdx.x >> 3);
    const int bh = bid / 48;
    const int chunk = bid - bh * 48;
    const int t0p = chunk * 32;
    const int b = bh >> 3, h = bh & 7;
    const int l = tid & 63;
    const int wv = tid >> 6;
    const int w4 = wv * 4;
    const int dpv = l & 31, halfw = l >> 5;
    const float S6 = 1.0f / 6.0f;
    const int lr = l & 15, grp = l >> 4;

    // ---- MFMA QK^T: wave wv computes S^T[n in wv*64..+64][t in t0p..+32]
    {
        const int n0 = wv * 64;
        const _Float16* kh = Kph + ((size_t)bh * 512 + n0 + lr) * 40;
        const _Float16* kl = Kpl + ((size_t)bh * 512 + n0 + lr) * 40;
        const _Float16* qh = Qph + ((size_t)bh * 1536 + t0p + lr) * 40;
        const _Float16* ql = Qpl + ((size_t)bh * 1536 + t0p + lr) * 40;

        f32x4 acc[4][2];
        #pragma unroll
        for (int mt = 0; mt < 4; ++mt) {
            acc[mt][0] = (f32x4){0.f, 0.f, 0.f, 0.f};
            acc[mt][1] = (f32x4){0.f, 0.f, 0.f, 0.f};
        }

        // kstep 0: d = grp*8 .. +8
        {
            const int doff = grp * 8;
            half8 ah[4], al[4], bh8[2], bl8[2];
            #pragma unroll
            for (int mt = 0; mt < 4; ++mt) {
                ah[mt] = *(const half8*)(kh + (size_t)mt * 640 + doff);
                al[mt] = *(const half8*)(kl + (size_t)mt * 640 + doff);
            }
            #pragma unroll
            for (int nt = 0; nt < 2; ++nt) {
                bh8[nt] = *(const half8*)(qh + (size_t)nt * 640 + doff);
                bl8[nt] = *(const half8*)(ql + (size_t)nt * 640 + doff);
            }
            #pragma unroll
            for (int mt = 0; mt < 4; ++mt)
                #pragma unroll
                for (int nt = 0; nt < 2; ++nt) {
                    acc[mt][nt] = __builtin_amdgcn_mfma_f32_16x16x32_f16(ah[mt], bh8[nt], acc[mt][nt], 0, 0, 0);
                    acc[mt][nt] = __builtin_amdgcn_mfma_f32_16x16x32_f16(ah[mt], bl8[nt], acc[mt][nt], 0, 0, 0);
                    acc[mt][nt] = __builtin_amdgcn_mfma_f32_16x16x32_f16(al[mt], bh8[nt], acc[mt][nt], 0, 0, 0);
                }
        }
        // kstep 1: d = 32 + grp*8; real data only for grp 0 (cols 36..40 zeroed)
        {
            half8 zz = {0, 0, 0, 0, 0, 0, 0, 0};
            half8 ah[4], al[4], bh8[2], bl8[2];
            bool has = (grp == 0);
            #pragma unroll
            for (int mt = 0; mt < 4; ++mt) {
                ah[mt] = has ? *(const half8*)(kh + (size_t)mt * 640 + 32) : zz;
                al[mt] = has ? *(const half8*)(kl + (size_t)mt * 640 + 32) : zz;
            }
            #pragma unroll
            for (int nt = 0; nt < 2; ++nt) {
                bh8[nt] = has ? *(const half8*)(qh + (size_t)nt * 640 + 32) : zz;
                bl8[nt] = has ? *(const half8*)(ql + (size_t)nt * 640 + 32) : zz;
            }
            #pragma unroll
            for (int mt = 0; mt < 4; ++mt)
                #pragma unroll
                for (int nt = 0; nt < 2; ++nt) {
                    acc[mt][nt] = __builtin_amdgcn_mfma_f32_16x16x32_f16(ah[mt], bh8[nt], acc[mt][nt], 0, 0, 0);
                    acc[mt][nt] = __builtin_amdgcn_mfma_f32_16x16x32_f16(ah[mt], bl8[nt], acc[mt][nt], 0, 0, 0);
                    acc[mt][nt] = __builtin_amdgcn_mfma_f32_16x16x32_f16(al[mt], bh8[nt], acc[mt][nt], 0, 0, 0);
                }
        }
        // write S^T/6: D row = grp*4+j -> n, col = lr -> t
        #pragma unroll
        for (int mt = 0; mt < 4; ++mt)
            #pragma unroll
            for (int nt = 0; nt < 2; ++nt) {
                int tl = nt * 16 + lr;
                int nb = n0 + mt * 16 + grp * 4;
                float4 v;
                v.x = acc[mt][nt][0] * S6; v.y = acc[mt][nt][1] * S6;
                v.z = acc[mt][nt][2] * S6; v.w = acc[mt][nt][3] * S6;
                *(float4*)&S_lds[tl * 516 + nb] = v;
            }
    }

    // u loads in flight across the barrier wait
    float4 ub0[4], ub1[4];
    {
        const float* ubase = un + ((size_t)bh * 1536 + t0p + w4) * 512;
        #pragma unroll
        for (int r = 0; r < 4; ++r) {
            ub0[r] = FI4(&ubase[(size_t)r * 512 + l * 4]);
            ub1[r] = FI4(&ubase[(size_t)r * 512 + 256 + l * 4]);
        }
    }
    __syncthreads();

    // ---- selection: wave wv owns rows w4..w4+3; slot j -> n = (j>>2)*256 + l*4 + (j&3)
    float acc[4][8];
    unsigned key[4][8];
    float m[4];
    #pragma unroll
    for (int r = 0; r < 4; ++r) {
        float4 s0 = FI4(&S_lds[(w4 + r) * 516 + l * 4]);
        float4 s1 = FI4(&S_lds[(w4 + r) * 516 + 256 + l * 4]);
        acc[r][0] = s0.x + gumbelf(ub0[r].x);
        acc[r][1] = s0.y + gumbelf(ub0[r].y);
        acc[r][2] = s0.z + gumbelf(ub0[r].z);
        acc[r][3] = s0.w + gumbelf(ub0[r].w);
        acc[r][4] = s1.x + gumbelf(ub1[r].x);
        acc[r][5] = s1.y + gumbelf(ub1[r].y);
        acc[r][6] = s1.z + gumbelf(ub1[r].z);
        acc[r][7] = s1.w + gumbelf(ub1[r].w);
        float mr = acc[r][0];
        #pragma unroll
        for (int j = 0; j < 8; ++j) {
            key[r][j] = ordkey(acc[r][j]);
            mr = fmaxf(mr, acc[r][j]);
        }
        m[r] = wave_max_bcast(mr);
    }

    #pragma unroll
    for (int pr = 0; pr < 2; ++pr) {
        const int rA = pr * 2, rB = pr * 2 + 1;

        unsigned long long selA[8], selB[8];
        select16_pair(key[rA], key[rB], selA, selB,
                      ordkey(m[rA] - 8.0f), ordkey(m[rA]),
                      ordkey(m[rB] - 8.0f), ordkey(m[rB]));

        // exp + sum + ballot-rank compaction
        float psA = 0.f, psB = 0.f;
        {
            int baseA = 0, baseB = 0;
            #pragma unroll
            for (int j = 0; j < 8; ++j) {
                unsigned long long ma = selA[j], mb = selB[j];
                int nj = ((j >> 2) << 8) + l * 4 + (j & 3);
                if ((ma >> l) & 1ull) {
                    float ex = __expf(acc[rA][j] - m[rA]);
                    psA += ex;
                    int rank = baseA + mbcnt64(ma);
                    CmpN[wv][pr][0][rank] = nj;
                    CmpW[wv][pr][0][rank] = ex;
                }
                if ((mb >> l) & 1ull) {
                    float ex = __expf(acc[rB][j] - m[rB]);
                    psB += ex;
                    int rank = baseB + mbcnt64(mb);
                    CmpN[wv][pr][1][rank] = nj;
                    CmpW[wv][pr][1][rank] = ex;
                }
                baseA += __popcll(ma); baseB += __popcll(mb);
            }
        }
        float sumA = wave_sum_bcast(psA);
        float sumB = wave_sum_bcast(psB);
        asm volatile("s_waitcnt lgkmcnt(0)" ::: "memory");

        // fixed 16-iter gather: independent V-row loads
        const float* Vbh = Vb + (size_t)bh * 18432;
        float od = 0.f, od2 = 0.f;
        #pragma unroll
        for (int k = 0; k < 16; ++k) {
            int nn  = CmpN[wv][pr][halfw][k];
            float w = CmpW[wv][pr][halfw][k];
            const float* vr = Vbh + (size_t)nn * 36;
            od = fmaf(w, vr[dpv], od);
            if (dpv < 4) od2 = fmaf(w, vr[32 + dpv], od2);
        }

        float invs = 1.0f / (halfw ? sumB : sumA);
        int t = t0p + w4 + pr * 2 + halfw;
        _Float16* orow = att16 + ((size_t)b * 1536 + t) * 288 + h * 36;
        orow[dpv] = (_Float16)(od * invs);
        if (dpv < 4) orow[32 + dpv] = (_Float16)(od2 * invs);
    }
}

// ---------------------------------------------------------------------------
extern "C" void kernel_launch(void* const* d_in, const int* in_sizes, int n_in,
                              void* d_out, int out_size, void* d_ws, size_t ws_size,
                              hipStream_t stream)
{
    (void)in_sizes; (void)n_in; (void)out_size; (void)ws_size;
    const float* x1      = (const float*)d_in[0];
    const float* x2      = (const float*)d_in[1];
    const float* x3      = (const float*)d_in[2];
    const float* xf      = (const float*)d_in[3];
    const float* emb     = (const float*)d_in[4];
    const float* un      = (const float*)d_in[5];
    const float* adaln_w = (const float*)d_in[6];
    const float* adaln_b = (const float*)d_in[7];
    const float* xfn_w   = (const float*)d_in[8];
    const float* xfn_b   = (const float*)d_in[9];
    const float* q_w     = (const float*)d_in[10];
    const float* q_b     = (const float*)d_in[11];
    const float* k_w     = (const float*)d_in[12];
    const float* k_b     = (const float*)d_in[13];
    const float* v_w     = (const float*)d_in[14];
    const float* v_b     = (const float*)d_in[15];
    const float* out_w   = (const float*)d_in[16];
    const float* out_b   = (const float*)d_in[17];
    float* out = (float*)d_out;

    float* ws = (float*)d_ws;
    float* eo = ws;                          // 16,384 f32
    float* Vb = eo + 16384;                  // 589,824 f32  [bh][512][36]
    _Float16* Qph = (_Float16*)(Vb + 589824);    // 1,966,080 h  [bh*1536][40]
    _Float16* Qpl = Qph + 1966080;
    _Float16* Kph = Qpl + 1966080;           // 655,360 h  [bh*512][40]
    _Float16* Kpl = Kph + 655360;
    _Float16* xnqh = Kpl + 655360;           // 3,145,728 h
    _Float16* xnql = xnqh + 3145728;
    _Float16* xfnh = xnql + 3145728;         // 8,388,608 h
    _Float16* xfnl = xfnh + 8388608;
    _Float16* att16 = xfnl + 8388608;        // 1,769,472 h
    _Float16* qwh  = att16 + 1769472;        // 442,368 h
    _Float16* qwl  = qwh + 442368;
    _Float16* kwh  = qwl + 442368;           // 147,456 h
    _Float16* kwl  = kwh + 147456;
    _Float16* vw16 = kwl + 147456;           // 147,456 h
    _Float16* ow16 = vw16 + 147456;          // 442,368 h

    prep_kernel<<<8960, 256, 0, stream>>>(q_w, k_w, v_w, out_w, emb,
                                          adaln_w, adaln_b, xfn_w, xfn_b,
                                          qwh, qwl, kwh, kwl, vw16, ow16,
                                          Qph, Qpl, Kph, Kpl, eo);
    ln_kernel<<<22528, 256, 0, stream>>>(x1, x2, x3, xf, eo, xnqh, xnql, xfnh, xfnl);
    qkv_kernel<<<544, 256, 0, stream>>>(xnqh, xnql, xfnh, xfnl,
                                        qwh, qwl, kwh, kwl, vw16,
                                        q_b, k_b, v_b, Qph, Qpl, Kph, Kpl, Vb);
    attn_kernel<<<1536, 512, 0, stream>>>(Qph, Qpl, Kph, Kpl, Vb, un, att16);
    outproj_kernel<<<384, 256, 0, stream>>>(att16, ow16, out_b, out);
}

// Round 15
// 170.543 us; speedup vs baseline: 1.4329x; 1.0706x over previous
//
#include <hip/hip_runtime.h>
#include <math.h>

#define FI4(p) (*(const float4*)(p))

typedef _Float16 half8 __attribute__((ext_vector_type(8)));
typedef _Float16 half2v __attribute__((ext_vector_type(2)));
typedef float f32x4 __attribute__((ext_vector_type(4)));

__device__ __forceinline__ float gumbelf(float u) {
    return -__logf(-__logf(u + 1e-9f) + 1e-9f);
}

template<int CTRL>
__device__ __forceinline__ int dppmov(int v) {
    return __builtin_amdgcn_update_dpp(v, v, CTRL, 0xF, 0xF, false);
}
__device__ __forceinline__ float wave_max_bcast(float v) {
    v = fmaxf(v, __int_as_float(dppmov<0xB1>(__float_as_int(v))));
    v = fmaxf(v, __int_as_float(dppmov<0x4E>(__float_as_int(v))));
    v = fmaxf(v, __int_as_float(dppmov<0x141>(__float_as_int(v))));
    v = fmaxf(v, __int_as_float(dppmov<0x140>(__float_as_int(v))));
    v = fmaxf(v, __int_as_float(dppmov<0x142>(__float_as_int(v))));
    v = fmaxf(v, __int_as_float(dppmov<0x143>(__float_as_int(v))));
    return __int_as_float(__builtin_amdgcn_readlane(__float_as_int(v), 63));
}
__device__ __forceinline__ float wave_sum_bcast(float v) {
    v += __int_as_float(dppmov<0xB1>(__float_as_int(v)));
    v += __int_as_float(dppmov<0x4E>(__float_as_int(v)));
    v += __int_as_float(dppmov<0x141>(__float_as_int(v)));
    v += __int_as_float(dppmov<0x140>(__float_as_int(v)));
    v += __int_as_float(dppmov<0x142>(__float_as_int(v)));
    v += __int_as_float(dppmov<0x143>(__float_as_int(v)));
    return __int_as_float(__builtin_amdgcn_readlane(__float_as_int(v), 63));
}

__device__ __forceinline__ unsigned ordkey(float f) {
    unsigned x = __float_as_uint(f);
    return x ^ ((unsigned)((int)x >> 31) | 0x80000000u);
}

__device__ __forceinline__ int mbcnt64(unsigned long long m) {
    return __builtin_amdgcn_mbcnt_hi((unsigned)(m >> 32),
           __builtin_amdgcn_mbcnt_lo((unsigned)m, 0));
}

__device__ __forceinline__ void copy8(unsigned long long* dst, const unsigned long long* src) {
    #pragma unroll
    for (int j = 0; j < 8; ++j) dst[j] = src[j];
}

// ties at key == hi filled by smallest n; n = (j>>2)*256 + lane*4 + (j&3)
__device__ __forceinline__ void tie_fill(const unsigned* u, unsigned long long* sel, unsigned hi)
{
    unsigned long long eq[8];
    int mcnt = 0;
    #pragma unroll
    for (int j = 0; j < 8; ++j) {
        sel[j] = __ballot(u[j] > hi);
        eq[j]  = __ballot(u[j] == hi);
        mcnt += __popcll(sel[j]);
    }
    int r = 16 - mcnt;
    #pragma unroll
    for (int jhi = 0; jhi < 2; ++jhi) {
        if (r > 0) {
            unsigned long long any = eq[jhi*4] | eq[jhi*4+1] | eq[jhi*4+2] | eq[jhi*4+3];
            while (any && r > 0) {
                int lane = (int)__builtin_ctzll(any); any &= any - 1;
                #pragma unroll
                for (int jlo = 0; jlo < 4; ++jlo) {
                    int j2 = jhi * 4 + jlo;
                    if (r > 0 && ((eq[j2] >> lane) & 1ull)) { sel[j2] |= 1ull << lane; --r; }
                }
            }
        }
    }
}

// Dual top-16 bisection (rows A/B in lockstep; 16 ballots in flight / probe)
__device__ __forceinline__ void select16_pair(
    const unsigned* uA, const unsigned* uB,
    unsigned long long* selA, unsigned long long* selB,
    unsigned loA, unsigned hiA, unsigned loB, unsigned hiB)
{
    bool doneA = false, doneB = false;
    {
        unsigned long long mmA[8], mmB[8];
        int cA = 0, cB = 0;
        #pragma unroll
        for (int j = 0; j < 8; ++j) {
            mmA[j] = __ballot(uA[j] > loA); cA += __popcll(mmA[j]);
            mmB[j] = __ballot(uB[j] > loB); cB += __popcll(mmB[j]);
        }
        if (cA == 16) { copy8(selA, mmA); doneA = true; }
        else if (cA < 16) loA = 0u;   // fallback: full range (ordkey(finite) > 0)
        if (cB == 16) { copy8(selB, mmB); doneB = true; }
        else if (cB < 16) loB = 0u;
    }
    while ((!doneA && hiA - loA > 1u) || (!doneB && hiB - loB > 1u)) {
        bool pA = !doneA && (hiA - loA > 1u);
        bool pB = !doneB && (hiB - loB > 1u);
        unsigned midA = loA + ((hiA - loA) >> 1);
        unsigned midB = loB + ((hiB - loB) >> 1);
        unsigned long long mmA[8], mmB[8];
        int cA = 0, cB = 0;
        #pragma unroll
        for (int j = 0; j < 8; ++j) {
            mmA[j] = __ballot(uA[j] > midA); cA += __popcll(mmA[j]);
            mmB[j] = __ballot(uB[j] > midB); cB += __popcll(mmB[j]);
        }
        if (pA) {
            if (cA == 16) { copy8(selA, mmA); doneA = true; }
            else if (cA > 16) loA = midA; else hiA = midA;
        }
        if (pB) {
            if (cB == 16) { copy8(selB, mmB); doneB = true; }
            else if (cB > 16) loB = midB; else hiB = midB;
        }
    }
    if (!doneA) tie_fill(uA, selA, hiA);
    if (!doneB) tie_fill(uB, selB, hiB);
}

// ---------------------------------------------------------------------------
// Fused prep: [0,4608) weight convert; [4608,8704) eo; [8704,8960) zero d-pads
// of Qp/Kp rows (cols 36..40) so MFMA K-steps read zeros.
// ---------------------------------------------------------------------------
__global__ __launch_bounds__(256) void prep_kernel(
    const float* __restrict__ q_w, const float* __restrict__ k_w,
    const float* __restrict__ v_w, const float* __restrict__ out_w,
    const float* __restrict__ emb,
    const float* __restrict__ adaln_w, const float* __restrict__ adaln_b,
    const float* __restrict__ xfn_w,  const float* __restrict__ xfn_b,
    _Float16* __restrict__ qwh, _Float16* __restrict__ qwl,
    _Float16* __restrict__ kwh, _Float16* __restrict__ kwl,
    _Float16* __restrict__ vw16, _Float16* __restrict__ ow16,
    _Float16* __restrict__ Qph, _Float16* __restrict__ Qpl,
    _Float16* __restrict__ Kph, _Float16* __restrict__ Kpl,
    float* __restrict__ eo)
{
    if (blockIdx.x < 4608) {
        int idx = blockIdx.x * 256 + threadIdx.x;
        if (idx < 442368) {
            float x = q_w[idx];
            _Float16 hi = (_Float16)x;
            qwh[idx] = hi; qwl[idx] = (_Float16)(x - (float)hi);
        } else if (idx < 442368 + 147456) {
            int i = idx - 442368;
            float x = k_w[i];
            _Float16 hi = (_Float16)x;
            kwh[i] = hi; kwl[i] = (_Float16)(x - (float)hi);
        } else if (idx < 442368 + 294912) {
            int i = idx - 442368 - 147456;
            vw16[i] = (_Float16)v_w[i];
        } else {
            int i = idx - 442368 - 294912;
            ow16[i] = (_Float16)out_w[i];
        }
    } else if (blockIdx.x < 8704) {
        int wid  = (blockIdx.x - 4608) * 4 + (threadIdx.x >> 6);
        int lane = threadIdx.x & 63;
        int l = wid >> 12;
        int rem = wid & 4095;
        int b = rem >> 10;
        int o = rem & 1023;
        const float* wrow = (l < 3) ? (adaln_w + ((size_t)(l * 1024 + o)) * 512)
                                    : (xfn_w + (size_t)o * 512);
        const float* erow = emb + b * 512;
        float acc = 0.f;
        for (int d = lane; d < 512; d += 64) {
            float e = erow[d];
            float se = e / (1.f + __expf(-e));
            acc = fmaf(se, wrow[d], acc);
        }
        #pragma unroll
        for (int off = 32; off; off >>= 1) acc += __shfl_xor(acc, off, 64);
        if (lane == 0) {
            float bias = (l < 3) ? adaln_b[l * 1024 + o] : xfn_b[o];
            eo[wid] = acc + bias;
        }
    } else {
        int idx = (blockIdx.x - 8704) * 256 + threadIdx.x;   // < 65536
        short4 z = {0, 0, 0, 0};
        if (idx < 49152) {
            *(short4*)&Qph[(size_t)idx * 40 + 36] = z;
            *(short4*)&Qpl[(size_t)idx * 40 + 36] = z;
        } else {
            int i2 = idx - 49152;                             // < 16384
            *(short4*)&Kph[(size_t)i2 * 40 + 36] = z;
            *(short4*)&Kpl[(size_t)i2 * 40 + 36] = z;
        }
    }
}

// ---------------------------------------------------------------------------
// LayerNorm + modulation -> fp16 hi+lo planes
// ---------------------------------------------------------------------------
__global__ __launch_bounds__(256) void ln_kernel(
    const float* __restrict__ x1, const float* __restrict__ x2,
    const float* __restrict__ x3, const float* __restrict__ xf,
    const float* __restrict__ eo,
    _Float16* __restrict__ xnqh, _Float16* __restrict__ xnql,
    _Float16* __restrict__ xfnh, _Float16* __restrict__ xfnl)
{
    int row = blockIdx.x;
    const float* src; const float* eorow; _Float16* dh; _Float16* dl;
    if (row < 6144) {
        int l = row >> 11, idx = row & 2047, b = idx >> 9;
        const float* xp = (l == 0) ? x1 : (l == 1) ? x2 : x3;
        src = xp + (size_t)idx * 512;
        eorow = eo + (size_t)(l * 4 + b) * 1024;
        dh = xnqh + (size_t)row * 512;
        dl = xnql + (size_t)row * 512;
    } else {
        int rr = row - 6144; int b = rr >> 12;
        src = xf + (size_t)rr * 512;
        eorow = eo + (size_t)(12 + b) * 1024;
        dh = xfnh + (size_t)rr * 512;
        dl = xfnl + (size_t)rr * 512;
    }
    int tid = threadIdx.x;
    float2 vv = *(const float2*)(src + 2 * tid);
    float s = vv.x + vv.y;
    float q = fmaf(vv.x, vv.x, vv.y * vv.y);
    #pragma unroll
    for (int off = 32; off; off >>= 1) {
        s += __shfl_xor(s, off, 64);
        q += __shfl_xor(q, off, 64);
    }
    __shared__ float red[8];
    int wv = tid >> 6, lane = tid & 63;
    if (lane == 0) { red[wv] = s; red[4 + wv] = q; }
    __syncthreads();
    s = red[0] + red[1] + red[2] + red[3];
    q = red[4] + red[5] + red[6] + red[7];
    float mu  = s * (1.f / 512.f);
    float var = q * (1.f / 512.f) - mu * mu;
    float rs  = 1.f / sqrtf(var + 1e-6f);
    float2 sc = *(const float2*)(eorow + 2 * tid);
    float2 sh = *(const float2*)(eorow + 512 + 2 * tid);
    float r0 = (vv.x - mu) * rs * (1.f + sc.x) + sh.x;
    float r1 = (vv.y - mu) * rs * (1.f + sc.y) + sh.y;
    _Float16 h0 = (_Float16)r0, h1 = (_Float16)r1;
    half2v H = {h0, h1};
    half2v L = {(_Float16)(r0 - (float)h0), (_Float16)(r1 - (float)h1)};
    *(half2v*)(dh + 2 * tid) = H;
    *(half2v*)(dl + 2 * tid) = L;
}

// ---------------------------------------------------------------------------
// fp16 MFMA GEMM body, LDS-free, per-wave 32 x (NF*16) tile.
// MODE 0: Q-proj SPLIT  -> Qph/Qpl fp16 [bh*1536 rows][40] (d-pad zeros in prep)
// MODE 1: K-proj SPLIT  -> Kph/Kpl fp16 [bh*512 rows][40]
// MODE 2: V-proj single -> Vb f32 [bh][512][36]
// MODE 3: out-proj single (att16 [b][1536][288], A-rows remapped) -> d_out f32
// SPLIT: acc = Ah@Wh + Ah@Wl + Al@Wh
// ---------------------------------------------------------------------------
template<int NF, int MODE>
__device__ __forceinline__ void gemm16_body(
    int gw, int l,
    const _Float16* __restrict__ Ah, const _Float16* __restrict__ Al,
    const _Float16* __restrict__ Wh, const _Float16* __restrict__ Wl,
    const float* __restrict__ bias,
    float* __restrict__ Of, _Float16* __restrict__ Oh, _Float16* __restrict__ Ol)
{
    constexpr bool SPLIT = (MODE == 0 || MODE == 1);
    const int Kd = (MODE == 3) ? 288 : 512;
    const int NT = (MODE == 0) ? 6 : (MODE == 3) ? 8 : 1;
    const int mt = gw / NT, nt = gw - mt * NT;
    const int row0 = mt * 32;
    const int col0 = nt * (NF * 16);
    const int lr = l & 15, lk = (l >> 4) * 8;

    int lsel = 0, h = 0;
    if (MODE == 0)                   { lsel = row0 >> 11; }
    else if (MODE == 1 || MODE == 2) { h = (row0 >> 9) & 7; }
    else                             { lsel = row0 >> 11; }

    size_t arow0;
    if (MODE == 3) {
        int rb = row0 & 2047, bb = rb >> 9, t0 = rb & 511;
        arow0 = (size_t)bb * 1536 + (size_t)lsel * 512 + t0;
    } else {
        arow0 = (size_t)row0;
    }

    const _Float16* aph = Ah + (arow0 + lr) * Kd + lk;
    const _Float16* apl = SPLIT ? (Al + (arow0 + lr) * Kd + lk) : nullptr;

    const _Float16* bph[NF];
    const _Float16* bpl[NF];
    #pragma unroll
    for (int f = 0; f < NF; ++f) {
        int c = col0 + f * 16 + lr;
        int wr;
        if (MODE == 0)      wr = lsel * 288 + c;
        else if (MODE == 3) wr = lsel * 512 + c;
        else                wr = h * 36 + (c < 36 ? c : 0);   // clamp; write masked
        bph[f] = Wh + (size_t)wr * Kd + lk;
        if (SPLIT) bpl[f] = Wl + (size_t)wr * Kd + lk;
    }

    f32x4 acc[2][NF];
    #pragma unroll
    for (int mi = 0; mi < 2; ++mi)
        #pragma unroll
        for (int f = 0; f < NF; ++f) acc[mi][f] = (f32x4){0.f, 0.f, 0.f, 0.f};

    for (int kk = 0; kk < Kd; kk += 32) {
        half8 a0h = *(const half8*)(aph + kk);
        half8 a1h = *(const half8*)(aph + (size_t)16 * Kd + kk);
        half8 a0l, a1l;
        if constexpr (SPLIT) {
            a0l = *(const half8*)(apl + kk);
            a1l = *(const half8*)(apl + (size_t)16 * Kd + kk);
        }
        #pragma unroll
        for (int f = 0; f < NF; ++f) {
            half8 bh_ = *(const half8*)(bph[f] + kk);
            acc[0][f] = __builtin_amdgcn_mfma_f32_16x16x32_f16(a0h, bh_, acc[0][f], 0, 0, 0);
            acc[1][f] = __builtin_amdgcn_mfma_f32_16x16x32_f16(a1h, bh_, acc[1][f], 0, 0, 0);
            if constexpr (SPLIT) {
                half8 bl_ = *(const half8*)(bpl[f] + kk);
                acc[0][f] = __builtin_amdgcn_mfma_f32_16x16x32_f16(a0h, bl_, acc[0][f], 0, 0, 0);
                acc[1][f] = __builtin_amdgcn_mfma_f32_16x16x32_f16(a1h, bl_, acc[1][f], 0, 0, 0);
                acc[0][f] = __builtin_amdgcn_mfma_f32_16x16x32_f16(a0l, bh_, acc[0][f], 0, 0, 0);
                acc[1][f] = __builtin_amdgcn_mfma_f32_16x16x32_f16(a1l, bh_, acc[1][f], 0, 0, 0);
            }
        }
    }

    #pragma unroll
    for (int mi = 0; mi < 2; ++mi) {
        int rbase = row0 + mi * 16 + (l >> 4) * 4;
        #pragma unroll
        for (int f = 0; f < NF; ++f) {
            int c = col0 + f * 16 + (l & 15);
            if (MODE == 0) {
                int hh = c / 36, hd = c - hh * 36;
                float bz = bias[lsel * 288 + c];
                #pragma unroll
                for (int j = 0; j < 4; ++j) {
                    int r = rbase + j;
                    int rb = r & 2047, bb2 = rb >> 9, t = rb & 511;
                    size_t row = ((size_t)bb2 * 8 + hh) * 1536 + lsel * 512 + t;
                    float v = acc[mi][f][j] + bz;
                    _Float16 hi = (_Float16)v;
                    Oh[row * 40 + hd] = hi;
                    Ol[row * 40 + hd] = (_Float16)(v - (float)hi);
                }
            } else if (MODE == 1) {
                if (c < 36) {
                    int bb2 = row0 >> 12;
                    int n0 = rbase & 511;
                    float bz = bias[h * 36 + c];
                    #pragma unroll
                    for (int j = 0; j < 4; ++j) {
                        size_t row = ((size_t)bb2 * 8 + h) * 512 + n0 + j;
                        float v = acc[mi][f][j] + bz;
                        _Float16 hi = (_Float16)v;
                        Oh[row * 40 + c] = hi;
                        Ol[row * 40 + c] = (_Float16)(v - (float)hi);
                    }
                }
            } else if (MODE == 2) {
                if (c < 36) {
                    int bb2 = row0 >> 12;
                    int n0 = rbase & 511;
                    float bz = bias[h * 36 + c];
                    #pragma unroll
                    for (int j = 0; j < 4; ++j)
                        Of[(((size_t)bb2 * 8 + h) * 512 + n0 + j) * 36 + c]
                            = acc[mi][f][j] + bz;
                }
            } else {
                float bz = bias[lsel * 512 + c];
                #pragma unroll
                for (int j = 0; j < 4; ++j) {
                    int r = rbase + j;
                    int rb = r & 2047, bb2 = rb >> 9, t = rb & 511;
                    Of[(size_t)lsel * 1048576 + ((size_t)bb2 * 512 + t) * 512 + c]
                        = acc[mi][f][j] + bz;
                }
            }
        }
    }
}

// Fused Q/K/V projections: blocks [0,288) Q, [288,416) K, [416,544) V
__global__ __launch_bounds__(256) void qkv_kernel(
    const _Float16* __restrict__ xnqh, const _Float16* __restrict__ xnql,
    const _Float16* __restrict__ xfnh, const _Float16* __restrict__ xfnl,
    const _Float16* __restrict__ qwh,  const _Float16* __restrict__ qwl,
    const _Float16* __restrict__ kwh,  const _Float16* __restrict__ kwl,
    const _Float16* __restrict__ vw16,
    const float* __restrict__ q_b, const float* __restrict__ k_b,
    const float* __restrict__ v_b,
    _Float16* __restrict__ Qph, _Float16* __restrict__ Qpl,
    _Float16* __restrict__ Kph, _Float16* __restrict__ Kpl,
    float* __restrict__ Vb)
{
    const int l = threadIdx.x & 63;
    const int w = threadIdx.x >> 6;
    if (blockIdx.x < 288)
        gemm16_body<3, 0>(blockIdx.x * 4 + w, l, xnqh, xnql, qwh, qwl, q_b,
                          nullptr, Qph, Qpl);
    else if (blockIdx.x < 416)
        gemm16_body<3, 1>((blockIdx.x - 288) * 4 + w, l, xfnh, xfnl, kwh, kwl, k_b,
                          nullptr, Kph, Kpl);
    else
        gemm16_body<3, 2>((blockIdx.x - 416) * 4 + w, l, xfnh, nullptr, vw16, nullptr, v_b,
                          Vb, nullptr, nullptr);
}

// out-proj standalone
__global__ __launch_bounds__(256) void outproj_kernel(
    const _Float16* __restrict__ att16, const _Float16* __restrict__ ow16,
    const float* __restrict__ out_b, float* __restrict__ out)
{
    const int l = threadIdx.x & 63;
    const int w = threadIdx.x >> 6;
    gemm16_body<4, 3>(blockIdx.x * 4 + w, l, att16, nullptr, ow16, nullptr, out_b,
                      out, nullptr, nullptr);
}

// ---------------------------------------------------------------------------
// Attention: 16-row chunks (3072 blocks, XCD-swizzled) -> 35 KB LDS ->
// 4 blocks/CU residency. MFMA QK^T (split fp16) -> S/6 into bank-padded LDS
// -> barrier -> pair-bisect selection + ballot-rank compaction + fixed
// 16-iter PV gather. Each wave owns 2 t-rows.
// ---------------------------------------------------------------------------
__global__ __launch_bounds__(512, 4) void attn_kernel(
    const _Float16* __restrict__ Qph, const _Float16* __restrict__ Qpl,
    const _Float16* __restrict__ Kph, const _Float16* __restrict__ Kpl,
    const float* __restrict__ Vb, const float* __restrict__ un,
    _Float16* __restrict__ att16)
{
    __shared__ float S_lds[16 * 516];
    __shared__ float CmpW[8][2][16];
    __shared__ int   CmpN[8][2][16];

    const int tid = threadIdx.x;
    // XCD swizzle: 3072 % 8 == 0 -> bijective; same-bh chunks share an XCD L2
    const int bid = ((int)blockIdx.x & 7) * 384 + ((int)blockIdx.x >> 3);
    const int bh = bid / 96;
    const int chunk = bid - bh * 96;
    const int t0p = chunk * 16;
    const int b = bh >> 3, h = bh & 7;
    const int l = tid & 63;
    const int wv = tid >> 6;
    const int w2 = wv * 2;
    const int dpv = l & 31, halfw = l >> 5;
    const float S6 = 1.0f / 6.0f;
    const int lr = l & 15, grp = l >> 4;

    // ---- MFMA QK^T: wave wv computes S^T[n in wv*64..+64][t0p..+16]
    {
        const int n0 = wv * 64;
        const _Float16* kh = Kph + ((size_t)bh * 512 + n0 + lr) * 40;
        const _Float16* kl = Kpl + ((size_t)bh * 512 + n0 + lr) * 40;
        const _Float16* qh = Qph + ((size_t)bh * 1536 + t0p + lr) * 40;
        const _Float16* ql = Qpl + ((size_t)bh * 1536 + t0p + lr) * 40;

        f32x4 acc[4];
        #pragma unroll
        for (int mt = 0; mt < 4; ++mt) acc[mt] = (f32x4){0.f, 0.f, 0.f, 0.f};

        // kstep 0: d = grp*8 .. +8
        {
            const int doff = grp * 8;
            half8 ah[4], al[4], bh8, bl8;
            #pragma unroll
            for (int mt = 0; mt < 4; ++mt) {
                ah[mt] = *(const half8*)(kh + (size_t)mt * 640 + doff);
                al[mt] = *(const half8*)(kl + (size_t)mt * 640 + doff);
            }
            bh8 = *(const half8*)(qh + doff);
            bl8 = *(const half8*)(ql + doff);
            #pragma unroll
            for (int mt = 0; mt < 4; ++mt) {
                acc[mt] = __builtin_amdgcn_mfma_f32_16x16x32_f16(ah[mt], bh8, acc[mt], 0, 0, 0);
                acc[mt] = __builtin_amdgcn_mfma_f32_16x16x32_f16(ah[mt], bl8, acc[mt], 0, 0, 0);
                acc[mt] = __builtin_amdgcn_mfma_f32_16x16x32_f16(al[mt], bh8, acc[mt], 0, 0, 0);
            }
        }
        // kstep 1: d = 32 + grp*8; real data only for grp 0 (cols 36..40 zeroed)
        {
            half8 zz = {0, 0, 0, 0, 0, 0, 0, 0};
            half8 ah[4], al[4], bh8, bl8;
            bool has = (grp == 0);
            #pragma unroll
            for (int mt = 0; mt < 4; ++mt) {
                ah[mt] = has ? *(const half8*)(kh + (size_t)mt * 640 + 32) : zz;
                al[mt] = has ? *(const half8*)(kl + (size_t)mt * 640 + 32) : zz;
            }
            bh8 = has ? *(const half8*)(qh + 32) : zz;
            bl8 = has ? *(const half8*)(ql + 32) : zz;
            #pragma unroll
            for (int mt = 0; mt < 4; ++mt) {
                acc[mt] = __builtin_amdgcn_mfma_f32_16x16x32_f16(ah[mt], bh8, acc[mt], 0, 0, 0);
                acc[mt] = __builtin_amdgcn_mfma_f32_16x16x32_f16(ah[mt], bl8, acc[mt], 0, 0, 0);
                acc[mt] = __builtin_amdgcn_mfma_f32_16x16x32_f16(al[mt], bh8, acc[mt], 0, 0, 0);
            }
        }
        // write S^T/6: D row = grp*4+j -> n, col = lr -> t
        #pragma unroll
        for (int mt = 0; mt < 4; ++mt) {
            int nb = n0 + mt * 16 + grp * 4;
            float4 v;
            v.x = acc[mt][0] * S6; v.y = acc[mt][1] * S6;
            v.z = acc[mt][2] * S6; v.w = acc[mt][3] * S6;
            *(float4*)&S_lds[lr * 516 + nb] = v;
        }
    }

    // u loads in flight across the barrier wait (wave's 2 rows)
    float4 ub0[2], ub1[2];
    {
        const float* ubase = un + ((size_t)bh * 1536 + t0p + w2) * 512;
        #pragma unroll
        for (int r = 0; r < 2; ++r) {
            ub0[r] = FI4(&ubase[(size_t)r * 512 + l * 4]);
            ub1[r] = FI4(&ubase[(size_t)r * 512 + 256 + l * 4]);
        }
    }
    __syncthreads();

    // ---- selection: wave wv owns rows w2, w2+1; slot j -> n = (j>>2)*256 + l*4 + (j&3)
    float acc[2][8];
    unsigned key[2][8];
    float m[2];
    #pragma unroll
    for (int r = 0; r < 2; ++r) {
        float4 s0 = FI4(&S_lds[(w2 + r) * 516 + l * 4]);
        float4 s1 = FI4(&S_lds[(w2 + r) * 516 + 256 + l * 4]);
        acc[r][0] = s0.x + gumbelf(ub0[r].x);
        acc[r][1] = s0.y + gumbelf(ub0[r].y);
        acc[r][2] = s0.z + gumbelf(ub0[r].z);
        acc[r][3] = s0.w + gumbelf(ub0[r].w);
        acc[r][4] = s1.x + gumbelf(ub1[r].x);
        acc[r][5] = s1.y + gumbelf(ub1[r].y);
        acc[r][6] = s1.z + gumbelf(ub1[r].z);
        acc[r][7] = s1.w + gumbelf(ub1[r].w);
        float mr = acc[r][0];
        #pragma unroll
        for (int j = 0; j < 8; ++j) {
            key[r][j] = ordkey(acc[r][j]);
            mr = fmaxf(mr, acc[r][j]);
        }
        m[r] = wave_max_bcast(mr);
    }

    unsigned long long selA[8], selB[8];
    select16_pair(key[0], key[1], selA, selB,
                  ordkey(m[0] - 8.0f), ordkey(m[0]),
                  ordkey(m[1] - 8.0f), ordkey(m[1]));

    // exp + sum + ballot-rank compaction
    float psA = 0.f, psB = 0.f;
    {
        int baseA = 0, baseB = 0;
        #pragma unroll
        for (int j = 0; j < 8; ++j) {
            unsigned long long ma = selA[j], mb = selB[j];
            int nj = ((j >> 2) << 8) + l * 4 + (j & 3);
            if ((ma >> l) & 1ull) {
                float ex = __expf(acc[0][j] - m[0]);
                psA += ex;
                int rank = baseA + mbcnt64(ma);
                CmpN[wv][0][rank] = nj;
                CmpW[wv][0][rank] = ex;
            }
            if ((mb >> l) & 1ull) {
                float ex = __expf(acc[1][j] - m[1]);
                psB += ex;
                int rank = baseB + mbcnt64(mb);
                CmpN[wv][1][rank] = nj;
                CmpW[wv][1][rank] = ex;
            }
            baseA += __popcll(ma); baseB += __popcll(mb);
        }
    }
    float sumA = wave_sum_bcast(psA);
    float sumB = wave_sum_bcast(psB);
    asm volatile("s_waitcnt lgkmcnt(0)" ::: "memory");

    // fixed 16-iter gather: half-wave 0 -> row w2, half-wave 1 -> row w2+1
    const float* Vbh = Vb + (size_t)bh * 18432;
    float od = 0.f, od2 = 0.f;
    #pragma unroll
    for (int k = 0; k < 16; ++k) {
        int nn  = CmpN[wv][halfw][k];
        float w = CmpW[wv][halfw][k];
        const float* vr = Vbh + (size_t)nn * 36;
        od = fmaf(w, vr[dpv], od);
        if (dpv < 4) od2 = fmaf(w, vr[32 + dpv], od2);
    }

    float invs = 1.0f / (halfw ? sumB : sumA);
    int t = t0p + w2 + halfw;
    _Float16* orow = att16 + ((size_t)b * 1536 + t) * 288 + h * 36;
    orow[dpv] = (_Float16)(od * invs);
    if (dpv < 4) orow[32 + dpv] = (_Float16)(od2 * invs);
}

// ---------------------------------------------------------------------------
extern "C" void kernel_launch(void* const* d_in, const int* in_sizes, int n_in,
                              void* d_out, int out_size, void* d_ws, size_t ws_size,
                              hipStream_t stream)
{
    (void)in_sizes; (void)n_in; (void)out_size; (void)ws_size;
    const float* x1      = (const float*)d_in[0];
    const float* x2      = (const float*)d_in[1];
    const float* x3      = (const float*)d_in[2];
    const float* xf      = (const float*)d_in[3];
    const float* emb     = (const float*)d_in[4];
    const float* un      = (const float*)d_in[5];
    const float* adaln_w = (const float*)d_in[6];
    const float* adaln_b = (const float*)d_in[7];
    const float* xfn_w   = (const float*)d_in[8];
    const float* xfn_b   = (const float*)d_in[9];
    const float* q_w     = (const float*)d_in[10];
    const float* q_b     = (const float*)d_in[11];
    const float* k_w     = (const float*)d_in[12];
    const float* k_b     = (const float*)d_in[13];
    const float* v_w     = (const float*)d_in[14];
    const float* v_b     = (const float*)d_in[15];
    const float* out_w   = (const float*)d_in[16];
    const float* out_b   = (const float*)d_in[17];
    float* out = (float*)d_out;

    float* ws = (float*)d_ws;
    float* eo = ws;                          // 16,384 f32
    float* Vb = eo + 16384;                  // 589,824 f32  [bh][512][36]
    _Float16* Qph = (_Float16*)(Vb + 589824);    // 1,966,080 h  [bh*1536][40]
    _Float16* Qpl = Qph + 1966080;
    _Float16* Kph = Qpl + 1966080;           // 655,360 h  [bh*512][40]
    _Float16* Kpl = Kph + 655360;
    _Float16* xnqh = Kpl + 655360;           // 3,145,728 h
    _Float16* xnql = xnqh + 3145728;
    _Float16* xfnh = xnql + 3145728;         // 8,388,608 h
    _Float16* xfnl = xfnh + 8388608;
    _Float16* att16 = xfnl + 8388608;        // 1,769,472 h
    _Float16* qwh  = att16 + 1769472;        // 442,368 h
    _Float16* qwl  = qwh + 442368;
    _Float16* kwh  = qwl + 442368;           // 147,456 h
    _Float16* kwl  = kwh + 147456;
    _Float16* vw16 = kwl + 147456;           // 147,456 h
    _Float16* ow16 = vw16 + 147456;          // 442,368 h

    prep_kernel<<<8960, 256, 0, stream>>>(q_w, k_w, v_w, out_w, emb,
                                          adaln_w, adaln_b, xfn_w, xfn_b,
                                          qwh, qwl, kwh, kwl, vw16, ow16,
                                          Qph, Qpl, Kph, Kpl, eo);
    ln_kernel<<<22528, 256, 0, stream>>>(x1, x2, x3, xf, eo, xnqh, xnql, xfnh, xfnl);
    qkv_kernel<<<544, 256, 0, stream>>>(xnqh, xnql, xfnh, xfnl,
                                        qwh, qwl, kwh, kwl, vw16,
                                        q_b, k_b, v_b, Qph, Qpl, Kph, Kpl, Vb);
    attn_kernel<<<3072, 512, 0, stream>>>(Qph, Qpl, Kph, Kpl, Vb, un, att16);
    outproj_kernel<<<384, 256, 0, stream>>>(att16, ow16, out_b, out);
}

// Round 16
// 151.759 us; speedup vs baseline: 1.6103x; 1.1238x over previous
//
#include <hip/hip_runtime.h>
#include <math.h>

#define FI4(p) (*(const float4*)(p))

typedef _Float16 half8 __attribute__((ext_vector_type(8)));
typedef _Float16 half2v __attribute__((ext_vector_type(2)));
typedef float f32x4 __attribute__((ext_vector_type(4)));

__device__ __forceinline__ float gumbelf(float u) {
    return -__logf(-__logf(u + 1e-9f) + 1e-9f);
}

template<int CTRL>
__device__ __forceinline__ int dppmov(int v) {
    return __builtin_amdgcn_update_dpp(v, v, CTRL, 0xF, 0xF, false);
}
__device__ __forceinline__ float wave_max_bcast(float v) {
    v = fmaxf(v, __int_as_float(dppmov<0xB1>(__float_as_int(v))));
    v = fmaxf(v, __int_as_float(dppmov<0x4E>(__float_as_int(v))));
    v = fmaxf(v, __int_as_float(dppmov<0x141>(__float_as_int(v))));
    v = fmaxf(v, __int_as_float(dppmov<0x140>(__float_as_int(v))));
    v = fmaxf(v, __int_as_float(dppmov<0x142>(__float_as_int(v))));
    v = fmaxf(v, __int_as_float(dppmov<0x143>(__float_as_int(v))));
    return __int_as_float(__builtin_amdgcn_readlane(__float_as_int(v), 63));
}
__device__ __forceinline__ float wave_sum_bcast(float v) {
    v += __int_as_float(dppmov<0xB1>(__float_as_int(v)));
    v += __int_as_float(dppmov<0x4E>(__float_as_int(v)));
    v += __int_as_float(dppmov<0x141>(__float_as_int(v)));
    v += __int_as_float(dppmov<0x140>(__float_as_int(v)));
    v += __int_as_float(dppmov<0x142>(__float_as_int(v)));
    v += __int_as_float(dppmov<0x143>(__float_as_int(v)));
    return __int_as_float(__builtin_amdgcn_readlane(__float_as_int(v), 63));
}

__device__ __forceinline__ unsigned ordkey(float f) {
    unsigned x = __float_as_uint(f);
    return x ^ ((unsigned)((int)x >> 31) | 0x80000000u);
}

__device__ __forceinline__ int mbcnt64(unsigned long long m) {
    return __builtin_amdgcn_mbcnt_hi((unsigned)(m >> 32),
           __builtin_amdgcn_mbcnt_lo((unsigned)m, 0));
}

// ties at key == hi filled by smallest n; n = (j>>2)*256 + lane*4 + (j&3)
__device__ __forceinline__ void tie_fill(const unsigned* u, unsigned long long* sel, unsigned hi)
{
    unsigned long long eq[8];
    int mcnt = 0;
    #pragma unroll
    for (int j = 0; j < 8; ++j) {
        sel[j] = __ballot(u[j] > hi);
        eq[j]  = __ballot(u[j] == hi);
        mcnt += __popcll(sel[j]);
    }
    int r = 16 - mcnt;
    #pragma unroll
    for (int jhi = 0; jhi < 2; ++jhi) {
        if (r > 0) {
            unsigned long long any = eq[jhi*4] | eq[jhi*4+1] | eq[jhi*4+2] | eq[jhi*4+3];
            while (any && r > 0) {
                int lane = (int)__builtin_ctzll(any); any &= any - 1;
                #pragma unroll
                for (int jlo = 0; jlo < 4; ++jlo) {
                    int j2 = jhi * 4 + jlo;
                    if (r > 0 && ((eq[j2] >> lane) & 1ull)) { sel[j2] |= 1ull << lane; --r; }
                }
            }
        }
    }
}

// Dual top-16: two-sided seeded bracket + count-only bisection (no per-probe
// mask saves); final single ballot pass builds sel at the found threshold.
// kL=ordkey(m-4.5), kM=ordkey(m-2.0), kT=ordkey(m). Invariants preserved by
// fallback bracket [0, kL] (ordkey(finite)>0 => cnt(>0)=512>16).
__device__ __forceinline__ void select16_pair(
    const unsigned* uA, const unsigned* uB,
    unsigned long long* selA, unsigned long long* selB,
    unsigned kL_A, unsigned kM_A, unsigned kT_A,
    unsigned kL_B, unsigned kM_B, unsigned kT_B)
{
    int cLA = 0, cMA = 0, cLB = 0, cMB = 0;
    #pragma unroll
    for (int j = 0; j < 8; ++j) {
        cLA += __popcll(__ballot(uA[j] > kL_A));
        cMA += __popcll(__ballot(uA[j] > kM_A));
        cLB += __popcll(__ballot(uB[j] > kL_B));
        cMB += __popcll(__ballot(uB[j] > kM_B));
    }
    unsigned loA, hiA, tauA = 0; bool doneA = false;
    if (cMA == 16)      { tauA = kM_A; doneA = true; }
    else if (cMA > 16)  { loA = kM_A; hiA = kT_A; }
    else if (cLA == 16) { tauA = kL_A; doneA = true; }
    else if (cLA > 16)  { loA = kL_A; hiA = kM_A; }
    else                { loA = 0u;   hiA = kL_A; }
    unsigned loB, hiB, tauB = 0; bool doneB = false;
    if (cMB == 16)      { tauB = kM_B; doneB = true; }
    else if (cMB > 16)  { loB = kM_B; hiB = kT_B; }
    else if (cLB == 16) { tauB = kL_B; doneB = true; }
    else if (cLB > 16)  { loB = kL_B; hiB = kM_B; }
    else                { loB = 0u;   hiB = kL_B; }

    while ((!doneA && hiA - loA > 1u) || (!doneB && hiB - loB > 1u)) {
        unsigned midA = loA + ((hiA - loA) >> 1);
        unsigned midB = loB + ((hiB - loB) >> 1);
        int cA = 0, cB = 0;
        #pragma unroll
        for (int j = 0; j < 8; ++j) {
            cA += __popcll(__ballot(uA[j] > midA));
            cB += __popcll(__ballot(uB[j] > midB));
        }
        if (!doneA && hiA - loA > 1u) {
            if (cA == 16) { tauA = midA; doneA = true; }
            else if (cA > 16) loA = midA; else hiA = midA;
        }
        if (!doneB && hiB - loB > 1u) {
            if (cB == 16) { tauB = midB; doneB = true; }
            else if (cB > 16) loB = midB; else hiB = midB;
        }
    }
    if (doneA) {
        #pragma unroll
        for (int j = 0; j < 8; ++j) selA[j] = __ballot(uA[j] > tauA);
    } else tie_fill(uA, selA, hiA);
    if (doneB) {
        #pragma unroll
        for (int j = 0; j < 8; ++j) selB[j] = __ballot(uB[j] > tauB);
    } else tie_fill(uB, selB, hiB);
}

// ---------------------------------------------------------------------------
// Fused prep: [0,4608) weight convert; [4608,8704) eo; [8704,8960) zero d-pads
// of Qp/Kp rows (cols 36..40) so MFMA K-steps read zeros.
// ---------------------------------------------------------------------------
__global__ __launch_bounds__(256) void prep_kernel(
    const float* __restrict__ q_w, const float* __restrict__ k_w,
    const float* __restrict__ v_w, const float* __restrict__ out_w,
    const float* __restrict__ emb,
    const float* __restrict__ adaln_w, const float* __restrict__ adaln_b,
    const float* __restrict__ xfn_w,  const float* __restrict__ xfn_b,
    _Float16* __restrict__ qwh, _Float16* __restrict__ qwl,
    _Float16* __restrict__ kwh, _Float16* __restrict__ kwl,
    _Float16* __restrict__ vw16, _Float16* __restrict__ ow16,
    _Float16* __restrict__ Qph, _Float16* __restrict__ Qpl,
    _Float16* __restrict__ Kph, _Float16* __restrict__ Kpl,
    float* __restrict__ eo)
{
    if (blockIdx.x < 4608) {
        int idx = blockIdx.x * 256 + threadIdx.x;
        if (idx < 442368) {
            float x = q_w[idx];
            _Float16 hi = (_Float16)x;
            qwh[idx] = hi; qwl[idx] = (_Float16)(x - (float)hi);
        } else if (idx < 442368 + 147456) {
            int i = idx - 442368;
            float x = k_w[i];
            _Float16 hi = (_Float16)x;
            kwh[i] = hi; kwl[i] = (_Float16)(x - (float)hi);
        } else if (idx < 442368 + 294912) {
            int i = idx - 442368 - 147456;
            vw16[i] = (_Float16)v_w[i];
        } else {
            int i = idx - 442368 - 294912;
            ow16[i] = (_Float16)out_w[i];
        }
    } else if (blockIdx.x < 8704) {
        int wid  = (blockIdx.x - 4608) * 4 + (threadIdx.x >> 6);
        int lane = threadIdx.x & 63;
        int l = wid >> 12;
        int rem = wid & 4095;
        int b = rem >> 10;
        int o = rem & 1023;
        const float* wrow = (l < 3) ? (adaln_w + ((size_t)(l * 1024 + o)) * 512)
                                    : (xfn_w + (size_t)o * 512);
        const float* erow = emb + b * 512;
        float acc = 0.f;
        for (int d = lane; d < 512; d += 64) {
            float e = erow[d];
            float se = e / (1.f + __expf(-e));
            acc = fmaf(se, wrow[d], acc);
        }
        #pragma unroll
        for (int off = 32; off; off >>= 1) acc += __shfl_xor(acc, off, 64);
        if (lane == 0) {
            float bias = (l < 3) ? adaln_b[l * 1024 + o] : xfn_b[o];
            eo[wid] = acc + bias;
        }
    } else {
        int idx = (blockIdx.x - 8704) * 256 + threadIdx.x;   // < 65536
        short4 z = {0, 0, 0, 0};
        if (idx < 49152) {
            *(short4*)&Qph[(size_t)idx * 40 + 36] = z;
            *(short4*)&Qpl[(size_t)idx * 40 + 36] = z;
        } else {
            int i2 = idx - 49152;                             // < 16384
            *(short4*)&Kph[(size_t)i2 * 40 + 36] = z;
            *(short4*)&Kpl[(size_t)i2 * 40 + 36] = z;
        }
    }
}

// ---------------------------------------------------------------------------
// LayerNorm + modulation -> fp16 hi+lo planes
// ---------------------------------------------------------------------------
__global__ __launch_bounds__(256) void ln_kernel(
    const float* __restrict__ x1, const float* __restrict__ x2,
    const float* __restrict__ x3, const float* __restrict__ xf,
    const float* __restrict__ eo,
    _Float16* __restrict__ xnqh, _Float16* __restrict__ xnql,
    _Float16* __restrict__ xfnh, _Float16* __restrict__ xfnl)
{
    int row = blockIdx.x;
    const float* src; const float* eorow; _Float16* dh; _Float16* dl;
    if (row < 6144) {
        int l = row >> 11, idx = row & 2047, b = idx >> 9;
        const float* xp = (l == 0) ? x1 : (l == 1) ? x2 : x3;
        src = xp + (size_t)idx * 512;
        eorow = eo + (size_t)(l * 4 + b) * 1024;
        dh = xnqh + (size_t)row * 512;
        dl = xnql + (size_t)row * 512;
    } else {
        int rr = row - 6144; int b = rr >> 12;
        src = xf + (size_t)rr * 512;
        eorow = eo + (size_t)(12 + b) * 1024;
        dh = xfnh + (size_t)rr * 512;
        dl = xfnl + (size_t)rr * 512;
    }
    int tid = threadIdx.x;
    float2 vv = *(const float2*)(src + 2 * tid);
    float s = vv.x + vv.y;
    float q = fmaf(vv.x, vv.x, vv.y * vv.y);
    #pragma unroll
    for (int off = 32; off; off >>= 1) {
        s += __shfl_xor(s, off, 64);
        q += __shfl_xor(q, off, 64);
    }
    __shared__ float red[8];
    int wv = tid >> 6, lane = tid & 63;
    if (lane == 0) { red[wv] = s; red[4 + wv] = q; }
    __syncthreads();
    s = red[0] + red[1] + red[2] + red[3];
    q = red[4] + red[5] + red[6] + red[7];
    float mu  = s * (1.f / 512.f);
    float var = q * (1.f / 512.f) - mu * mu;
    float rs  = 1.f / sqrtf(var + 1e-6f);
    float2 sc = *(const float2*)(eorow + 2 * tid);
    float2 sh = *(const float2*)(eorow + 512 + 2 * tid);
    float r0 = (vv.x - mu) * rs * (1.f + sc.x) + sh.x;
    float r1 = (vv.y - mu) * rs * (1.f + sc.y) + sh.y;
    _Float16 h0 = (_Float16)r0, h1 = (_Float16)r1;
    half2v H = {h0, h1};
    half2v L = {(_Float16)(r0 - (float)h0), (_Float16)(r1 - (float)h1)};
    *(half2v*)(dh + 2 * tid) = H;
    *(half2v*)(dl + 2 * tid) = L;
}

// ---------------------------------------------------------------------------
// fp16 MFMA GEMM body, LDS-free, per-wave 32 x (NF*16) tile.
// MODE 0: Q-proj SPLIT  -> Qph/Qpl fp16 [bh*1536 rows][40], PRE-SCALED by 1/6
// MODE 1: K-proj SPLIT  -> Kph/Kpl fp16 [bh*512 rows][40]
// MODE 2: V-proj single -> Vb f32 [bh][512][36]
// MODE 3: out-proj single (att16 [b][1536][288], A-rows remapped) -> d_out f32
// SPLIT: acc = Ah@Wh + Ah@Wl + Al@Wh
// ---------------------------------------------------------------------------
template<int NF, int MODE>
__device__ __forceinline__ void gemm16_body(
    int gw, int l,
    const _Float16* __restrict__ Ah, const _Float16* __restrict__ Al,
    const _Float16* __restrict__ Wh, const _Float16* __restrict__ Wl,
    const float* __restrict__ bias,
    float* __restrict__ Of, _Float16* __restrict__ Oh, _Float16* __restrict__ Ol)
{
    constexpr bool SPLIT = (MODE == 0 || MODE == 1);
    const int Kd = (MODE == 3) ? 288 : 512;
    const int NT = (MODE == 0) ? 6 : (MODE == 3) ? 8 : 1;
    const int mt = gw / NT, nt = gw - mt * NT;
    const int row0 = mt * 32;
    const int col0 = nt * (NF * 16);
    const int lr = l & 15, lk = (l >> 4) * 8;

    int lsel = 0, h = 0;
    if (MODE == 0)                   { lsel = row0 >> 11; }
    else if (MODE == 1 || MODE == 2) { h = (row0 >> 9) & 7; }
    else                             { lsel = row0 >> 11; }

    size_t arow0;
    if (MODE == 3) {
        int rb = row0 & 2047, bb = rb >> 9, t0 = rb & 511;
        arow0 = (size_t)bb * 1536 + (size_t)lsel * 512 + t0;
    } else {
        arow0 = (size_t)row0;
    }

    const _Float16* aph = Ah + (arow0 + lr) * Kd + lk;
    const _Float16* apl = SPLIT ? (Al + (arow0 + lr) * Kd + lk) : nullptr;

    const _Float16* bph[NF];
    const _Float16* bpl[NF];
    #pragma unroll
    for (int f = 0; f < NF; ++f) {
        int c = col0 + f * 16 + lr;
        int wr;
        if (MODE == 0)      wr = lsel * 288 + c;
        else if (MODE == 3) wr = lsel * 512 + c;
        else                wr = h * 36 + (c < 36 ? c : 0);   // clamp; write masked
        bph[f] = Wh + (size_t)wr * Kd + lk;
        if (SPLIT) bpl[f] = Wl + (size_t)wr * Kd + lk;
    }

    f32x4 acc[2][NF];
    #pragma unroll
    for (int mi = 0; mi < 2; ++mi)
        #pragma unroll
        for (int f = 0; f < NF; ++f) acc[mi][f] = (f32x4){0.f, 0.f, 0.f, 0.f};

    for (int kk = 0; kk < Kd; kk += 32) {
        half8 a0h = *(const half8*)(aph + kk);
        half8 a1h = *(const half8*)(aph + (size_t)16 * Kd + kk);
        half8 a0l, a1l;
        if constexpr (SPLIT) {
            a0l = *(const half8*)(apl + kk);
            a1l = *(const half8*)(apl + (size_t)16 * Kd + kk);
        }
        #pragma unroll
        for (int f = 0; f < NF; ++f) {
            half8 bh_ = *(const half8*)(bph[f] + kk);
            acc[0][f] = __builtin_amdgcn_mfma_f32_16x16x32_f16(a0h, bh_, acc[0][f], 0, 0, 0);
            acc[1][f] = __builtin_amdgcn_mfma_f32_16x16x32_f16(a1h, bh_, acc[1][f], 0, 0, 0);
            if constexpr (SPLIT) {
                half8 bl_ = *(const half8*)(bpl[f] + kk);
                acc[0][f] = __builtin_amdgcn_mfma_f32_16x16x32_f16(a0h, bl_, acc[0][f], 0, 0, 0);
                acc[1][f] = __builtin_amdgcn_mfma_f32_16x16x32_f16(a1h, bl_, acc[1][f], 0, 0, 0);
                acc[0][f] = __builtin_amdgcn_mfma_f32_16x16x32_f16(a0l, bh_, acc[0][f], 0, 0, 0);
                acc[1][f] = __builtin_amdgcn_mfma_f32_16x16x32_f16(a1l, bh_, acc[1][f], 0, 0, 0);
            }
        }
    }

    #pragma unroll
    for (int mi = 0; mi < 2; ++mi) {
        int rbase = row0 + mi * 16 + (l >> 4) * 4;
        #pragma unroll
        for (int f = 0; f < NF; ++f) {
            int c = col0 + f * 16 + (l & 15);
            if (MODE == 0) {
                int hh = c / 36, hd = c - hh * 36;
                float bz = bias[lsel * 288 + c];
                #pragma unroll
                for (int j = 0; j < 4; ++j) {
                    int r = rbase + j;
                    int rb = r & 2047, bb2 = rb >> 9, t = rb & 511;
                    size_t row = ((size_t)bb2 * 8 + hh) * 1536 + lsel * 512 + t;
                    float v = (acc[mi][f][j] + bz) * (1.0f / 6.0f);  // fold 1/6 here
                    _Float16 hi = (_Float16)v;
                    Oh[row * 40 + hd] = hi;
                    Ol[row * 40 + hd] = (_Float16)(v - (float)hi);
                }
            } else if (MODE == 1) {
                if (c < 36) {
                    int bb2 = row0 >> 12;
                    int n0 = rbase & 511;
                    float bz = bias[h * 36 + c];
                    #pragma unroll
                    for (int j = 0; j < 4; ++j) {
                        size_t row = ((size_t)bb2 * 8 + h) * 512 + n0 + j;
                        float v = acc[mi][f][j] + bz;
                        _Float16 hi = (_Float16)v;
                        Oh[row * 40 + c] = hi;
                        Ol[row * 40 + c] = (_Float16)(v - (float)hi);
                    }
                }
            } else if (MODE == 2) {
                if (c < 36) {
                    int bb2 = row0 >> 12;
                    int n0 = rbase & 511;
                    float bz = bias[h * 36 + c];
                    #pragma unroll
                    for (int j = 0; j < 4; ++j)
                        Of[(((size_t)bb2 * 8 + h) * 512 + n0 + j) * 36 + c]
                            = acc[mi][f][j] + bz;
                }
            } else {
                float bz = bias[lsel * 512 + c];
                #pragma unroll
                for (int j = 0; j < 4; ++j) {
                    int r = rbase + j;
                    int rb = r & 2047, bb2 = rb >> 9, t = rb & 511;
                    Of[(size_t)lsel * 1048576 + ((size_t)bb2 * 512 + t) * 512 + c]
                        = acc[mi][f][j] + bz;
                }
            }
        }
    }
}

// Fused Q/K/V projections: blocks [0,288) Q, [288,416) K, [416,544) V
__global__ __launch_bounds__(256) void qkv_kernel(
    const _Float16* __restrict__ xnqh, const _Float16* __restrict__ xnql,
    const _Float16* __restrict__ xfnh, const _Float16* __restrict__ xfnl,
    const _Float16* __restrict__ qwh,  const _Float16* __restrict__ qwl,
    const _Float16* __restrict__ kwh,  const _Float16* __restrict__ kwl,
    const _Float16* __restrict__ vw16,
    const float* __restrict__ q_b, const float* __restrict__ k_b,
    const float* __restrict__ v_b,
    _Float16* __restrict__ Qph, _Float16* __restrict__ Qpl,
    _Float16* __restrict__ Kph, _Float16* __restrict__ Kpl,
    float* __restrict__ Vb)
{
    const int l = threadIdx.x & 63;
    const int w = threadIdx.x >> 6;
    if (blockIdx.x < 288)
        gemm16_body<3, 0>(blockIdx.x * 4 + w, l, xnqh, xnql, qwh, qwl, q_b,
                          nullptr, Qph, Qpl);
    else if (blockIdx.x < 416)
        gemm16_body<3, 1>((blockIdx.x - 288) * 4 + w, l, xfnh, xfnl, kwh, kwl, k_b,
                          nullptr, Kph, Kpl);
    else
        gemm16_body<3, 2>((blockIdx.x - 416) * 4 + w, l, xfnh, nullptr, vw16, nullptr, v_b,
                          Vb, nullptr, nullptr);
}

// out-proj standalone
__global__ __launch_bounds__(256) void outproj_kernel(
    const _Float16* __restrict__ att16, const _Float16* __restrict__ ow16,
    const float* __restrict__ out_b, float* __restrict__ out)
{
    const int l = threadIdx.x & 63;
    const int w = threadIdx.x >> 6;
    gemm16_body<4, 3>(blockIdx.x * 4 + w, l, att16, nullptr, ow16, nullptr, out_b,
                      out, nullptr, nullptr);
}

// ---------------------------------------------------------------------------
// Attention: 16-row chunks (3072 blocks, XCD-swizzled), 35 KB LDS, 4 blk/CU.
// MFMA QK^T (split fp16, Q pre-scaled 1/6) -> S into bank-padded LDS ->
// barrier -> two-sided-seeded count-only bisection + ballot-rank compaction
// (unnormalized exp) + fixed 16-iter PV gather. Each wave owns 2 t-rows.
// ---------------------------------------------------------------------------
__global__ __launch_bounds__(512, 4) void attn_kernel(
    const _Float16* __restrict__ Qph, const _Float16* __restrict__ Qpl,
    const _Float16* __restrict__ Kph, const _Float16* __restrict__ Kpl,
    const float* __restrict__ Vb, const float* __restrict__ un,
    _Float16* __restrict__ att16)
{
    __shared__ float S_lds[16 * 516];
    __shared__ float CmpW[8][2][16];
    __shared__ int   CmpN[8][2][16];

    const int tid = threadIdx.x;
    // XCD swizzle: 3072 % 8 == 0 -> bijective; same-bh chunks share an XCD L2
    const int bid = ((int)blockIdx.x & 7) * 384 + ((int)blockIdx.x >> 3);
    const int bh = bid / 96;
    const int chunk = bid - bh * 96;
    const int t0p = chunk * 16;
    const int b = bh >> 3, h = bh & 7;
    const int l = tid & 63;
    const int wv = tid >> 6;
    const int w2 = wv * 2;
    const int dpv = l & 31, halfw = l >> 5;
    const int lr = l & 15, grp = l >> 4;

    // ---- MFMA QK^T: wave wv computes S^T[n in wv*64..+64][t0p..+16]
    {
        const int n0 = wv * 64;
        const _Float16* kh = Kph + ((size_t)bh * 512 + n0 + lr) * 40;
        const _Float16* kl = Kpl + ((size_t)bh * 512 + n0 + lr) * 40;
        const _Float16* qh = Qph + ((size_t)bh * 1536 + t0p + lr) * 40;
        const _Float16* ql = Qpl + ((size_t)bh * 1536 + t0p + lr) * 40;

        f32x4 acc[4];
        #pragma unroll
        for (int mt = 0; mt < 4; ++mt) acc[mt] = (f32x4){0.f, 0.f, 0.f, 0.f};

        // kstep 0: d = grp*8 .. +8
        {
            const int doff = grp * 8;
            half8 ah[4], al[4], bh8, bl8;
            #pragma unroll
            for (int mt = 0; mt < 4; ++mt) {
                ah[mt] = *(const half8*)(kh + (size_t)mt * 640 + doff);
                al[mt] = *(const half8*)(kl + (size_t)mt * 640 + doff);
            }
            bh8 = *(const half8*)(qh + doff);
            bl8 = *(const half8*)(ql + doff);
            #pragma unroll
            for (int mt = 0; mt < 4; ++mt) {
                acc[mt] = __builtin_amdgcn_mfma_f32_16x16x32_f16(ah[mt], bh8, acc[mt], 0, 0, 0);
                acc[mt] = __builtin_amdgcn_mfma_f32_16x16x32_f16(ah[mt], bl8, acc[mt], 0, 0, 0);
                acc[mt] = __builtin_amdgcn_mfma_f32_16x16x32_f16(al[mt], bh8, acc[mt], 0, 0, 0);
            }
        }
        // kstep 1: d = 32 + grp*8; real data only for grp 0 (cols 36..40 zeroed)
        {
            half8 zz = {0, 0, 0, 0, 0, 0, 0, 0};
            half8 ah[4], al[4], bh8, bl8;
            bool has = (grp == 0);
            #pragma unroll
            for (int mt = 0; mt < 4; ++mt) {
                ah[mt] = has ? *(const half8*)(kh + (size_t)mt * 640 + 32) : zz;
                al[mt] = has ? *(const half8*)(kl + (size_t)mt * 640 + 32) : zz;
            }
            bh8 = has ? *(const half8*)(qh + 32) : zz;
            bl8 = has ? *(const half8*)(ql + 32) : zz;
            #pragma unroll
            for (int mt = 0; mt < 4; ++mt) {
                acc[mt] = __builtin_amdgcn_mfma_f32_16x16x32_f16(ah[mt], bh8, acc[mt], 0, 0, 0);
                acc[mt] = __builtin_amdgcn_mfma_f32_16x16x32_f16(ah[mt], bl8, acc[mt], 0, 0, 0);
                acc[mt] = __builtin_amdgcn_mfma_f32_16x16x32_f16(al[mt], bh8, acc[mt], 0, 0, 0);
            }
        }
        // write S^T (already /6 via Q pre-scale): D row = grp*4+j -> n, col = lr -> t
        #pragma unroll
        for (int mt = 0; mt < 4; ++mt) {
            int nb = n0 + mt * 16 + grp * 4;
            float4 v;
            v.x = acc[mt][0]; v.y = acc[mt][1];
            v.z = acc[mt][2]; v.w = acc[mt][3];
            *(float4*)&S_lds[lr * 516 + nb] = v;
        }
    }

    // u loads in flight across the barrier wait (wave's 2 rows)
    float4 ub0[2], ub1[2];
    {
        const float* ubase = un + ((size_t)bh * 1536 + t0p + w2) * 512;
        #pragma unroll
        for (int r = 0; r < 2; ++r) {
            ub0[r] = FI4(&ubase[(size_t)r * 512 + l * 4]);
            ub1[r] = FI4(&ubase[(size_t)r * 512 + 256 + l * 4]);
        }
    }
    __syncthreads();

    // ---- selection: wave wv owns rows w2, w2+1; slot j -> n = (j>>2)*256 + l*4 + (j&3)
    float acc[2][8];
    unsigned key[2][8];
    float m[2];
    #pragma unroll
    for (int r = 0; r < 2; ++r) {
        float4 s0 = FI4(&S_lds[(w2 + r) * 516 + l * 4]);
        float4 s1 = FI4(&S_lds[(w2 + r) * 516 + 256 + l * 4]);
        acc[r][0] = s0.x + gumbelf(ub0[r].x);
        acc[r][1] = s0.y + gumbelf(ub0[r].y);
        acc[r][2] = s0.z + gumbelf(ub0[r].z);
        acc[r][3] = s0.w + gumbelf(ub0[r].w);
        acc[r][4] = s1.x + gumbelf(ub1[r].x);
        acc[r][5] = s1.y + gumbelf(ub1[r].y);
        acc[r][6] = s1.z + gumbelf(ub1[r].z);
        acc[r][7] = s1.w + gumbelf(ub1[r].w);
        float mr = acc[r][0];
        #pragma unroll
        for (int j = 0; j < 8; ++j) {
            key[r][j] = ordkey(acc[r][j]);
            mr = fmaxf(mr, acc[r][j]);
        }
        m[r] = wave_max_bcast(mr);
    }

    unsigned long long selA[8], selB[8];
    select16_pair(key[0], key[1], selA, selB,
                  ordkey(m[0] - 4.5f), ordkey(m[0] - 2.0f), ordkey(m[0]),
                  ordkey(m[1] - 4.5f), ordkey(m[1] - 2.0f), ordkey(m[1]));

    // unnormalized exp + sum + ballot-rank compaction (scale cancels in invs)
    float psA = 0.f, psB = 0.f;
    {
        int baseA = 0, baseB = 0;
        #pragma unroll
        for (int j = 0; j < 8; ++j) {
            unsigned long long ma = selA[j], mb = selB[j];
            int nj = ((j >> 2) << 8) + l * 4 + (j & 3);
            if ((ma >> l) & 1ull) {
                float ex = __expf(acc[0][j]);
                psA += ex;
                int rank = baseA + mbcnt64(ma);
                CmpN[wv][0][rank] = nj;
                CmpW[wv][0][rank] = ex;
            }
            if ((mb >> l) & 1ull) {
                float ex = __expf(acc[1][j]);
                psB += ex;
                int rank = baseB + mbcnt64(mb);
                CmpN[wv][1][rank] = nj;
                CmpW[wv][1][rank] = ex;
            }
            baseA += __popcll(ma); baseB += __popcll(mb);
        }
    }
    float sumA = wave_sum_bcast(psA);
    float sumB = wave_sum_bcast(psB);
    asm volatile("s_waitcnt lgkmcnt(0)" ::: "memory");

    // fixed 16-iter gather: half-wave 0 -> row w2, half-wave 1 -> row w2+1
    const float* Vbh = Vb + (size_t)bh * 18432;
    float od = 0.f, od2 = 0.f;
    #pragma unroll
    for (int k = 0; k < 16; ++k) {
        int nn  = CmpN[wv][halfw][k];
        float w = CmpW[wv][halfw][k];
        const float* vr = Vbh + (size_t)nn * 36;
        od = fmaf(w, vr[dpv], od);
        if (dpv < 4) od2 = fmaf(w, vr[32 + dpv], od2);
    }

    float invs = 1.0f / (halfw ? sumB : sumA);
    int t = t0p + w2 + halfw;
    _Float16* orow = att16 + ((size_t)b * 1536 + t) * 288 + h * 36;
    orow[dpv] = (_Float16)(od * invs);
    if (dpv < 4) orow[32 + dpv] = (_Float16)(od2 * invs);
}

// ---------------------------------------------------------------------------
extern "C" void kernel_launch(void* const* d_in, const int* in_sizes, int n_in,
                              void* d_out, int out_size, void* d_ws, size_t ws_size,
                              hipStream_t stream)
{
    (void)in_sizes; (void)n_in; (void)out_size; (void)ws_size;
    const float* x1      = (const float*)d_in[0];
    const float* x2      = (const float*)d_in[1];
    const float* x3      = (const float*)d_in[2];
    const float* xf      = (const float*)d_in[3];
    const float* emb     = (const float*)d_in[4];
    const float* un      = (const float*)d_in[5];
    const float* adaln_w = (const float*)d_in[6];
    const float* adaln_b = (const float*)d_in[7];
    const float* xfn_w   = (const float*)d_in[8];
    const float* xfn_b   = (const float*)d_in[9];
    const float* q_w     = (const float*)d_in[10];
    const float* q_b     = (const float*)d_in[11];
    const float* k_w     = (const float*)d_in[12];
    const float* k_b     = (const float*)d_in[13];
    const float* v_w     = (const float*)d_in[14];
    const float* v_b     = (const float*)d_in[15];
    const float* out_w   = (const float*)d_in[16];
    const float* out_b   = (const float*)d_in[17];
    float* out = (float*)d_out;

    float* ws = (float*)d_ws;
    float* eo = ws;                          // 16,384 f32
    float* Vb = eo + 16384;                  // 589,824 f32  [bh][512][36]
    _Float16* Qph = (_Float16*)(Vb + 589824);    // 1,966,080 h  [bh*1536][40]
    _Float16* Qpl = Qph + 1966080;
    _Float16* Kph = Qpl + 1966080;           // 655,360 h  [bh*512][40]
    _Float16* Kpl = Kph + 655360;
    _Float16* xnqh = Kpl + 655360;           // 3,145,728 h
    _Float16* xnql = xnqh + 3145728;
    _Float16* xfnh = xnql + 3145728;         // 8,388,608 h
    _Float16* xfnl = xfnh + 8388608;
    _Float16* att16 = xfnl + 8388608;        // 1,769,472 h
    _Float16* qwh  = att16 + 1769472;        // 442,368 h
    _Float16* qwl  = qwh + 442368;
    _Float16* kwh  = qwl + 442368;           // 147,456 h
    _Float16* kwl  = kwh + 147456;
    _Float16* vw16 = kwl + 147456;           // 147,456 h
    _Float16* ow16 = vw16 + 147456;          // 442,368 h

    prep_kernel<<<8960, 256, 0, stream>>>(q_w, k_w, v_w, out_w, emb,
                                          adaln_w, adaln_b, xfn_w, xfn_b,
                                          qwh, qwl, kwh, kwl, vw16, ow16,
                                          Qph, Qpl, Kph, Kpl, eo);
    ln_kernel<<<22528, 256, 0, stream>>>(x1, x2, x3, xf, eo, xnqh, xnql, xfnh, xfnl);
    qkv_kernel<<<544, 256, 0, stream>>>(xnqh, xnql, xfnh, xfnl,
                                        qwh, qwl, kwh, kwl, vw16,
                                        q_b, k_b, v_b, Qph, Qpl, Kph, Kpl, Vb);
    attn_kernel<<<3072, 512, 0, stream>>>(Qph, Qpl, Kph, Kpl, Vb, un, att16);
    outproj_kernel<<<384, 256, 0, stream>>>(att16, ow16, out_b, out);
}